// Round 1
// baseline (296.107 us; speedup 1.0000x reference)
//
#include <hip/hip_runtime.h>
#include <cmath>

#define NUM_CLS 58

typedef _Float16 v8h __attribute__((ext_vector_type(8)));
typedef float v4f __attribute__((ext_vector_type(4)));
union HU { v8h h; uint4 u; };

// ---------------- prep v3: 256-thread blocks, coalesced staging ----------------
// blocks 0..383   : per-oc binarize of w1/w2/w3 (layer=id>>7, oc=id&127)
// blocks 384..415 : w4 binarize (1 oc per wave)
// blocks 416..417 : w0 MFMA B-fragments, signed + abs (4 nt per block)
__global__ __launch_bounds__(256) void prep_all(
    const float* __restrict__ w0, const float* __restrict__ w1,
    const float* __restrict__ w2, const float* __restrict__ w3,
    const float* __restrict__ w4,
    unsigned long long* __restrict__ wb1, unsigned long long* __restrict__ wb2,
    unsigned long long* __restrict__ wb3, unsigned long long* __restrict__ wb4,
    _Float16* __restrict__ bsig, _Float16* __restrict__ babs) {
    int id = blockIdx.x, tid = threadIdx.x;
    int lane = tid & 63, wv = tid >> 6;
    if (id < 384) {
        int layer = id >> 7, oc = id & 127;
        const float* w = layer == 0 ? w1 : (layer == 1 ? w2 : w3);
        unsigned long long* o = layer == 0 ? wb1 : (layer == 1 ? wb2 : wb3);
        __shared__ float s[1152];
        const float* base = w + (size_t)oc * 1152;
        for (int i = tid; i < 1152; i += 256) s[i] = base[i];   // coalesced
        __syncthreads();
        for (int k = wv; k < 9; k += 4) {    // stride-9 LDS reads: 2-way banks, free
            unsigned long long b0 = __ballot(s[lane * 9 + k] >= 0.f);
            unsigned long long b1 = __ballot(s[(lane + 64) * 9 + k] >= 0.f);
            if (lane == 0) { o[(oc * 9 + k) * 2] = b0; o[(oc * 9 + k) * 2 + 1] = b1; }
        }
    } else if (id < 416) {
        int oc = (id - 384) * 4 + wv;        // 128 oc over 32 blocks x 4 waves
        unsigned long long b0 = __ballot(w4[oc * 128 + lane] >= 0.f);
        unsigned long long b1 = __ballot(w4[oc * 128 + lane + 64] >= 0.f);
        if (lane == 0) { wb4[oc * 2] = b0; wb4[oc * 2 + 1] = b1; }
    } else {
        int nt = (id - 416) * 4 + wv;        // 8 nt over 2 blocks x 4 waves
        int n = nt * 16 + (lane & 15);
        int k0 = (lane >> 4) * 8;
#pragma unroll
        for (int j = 0; j < 8; j++) {
            int k = k0 + j;
            float v = (k < 27) ? w0[n * 27 + k] : 0.f;
            bsig[(nt * 64 + lane) * 8 + j] = (_Float16)v;
            babs[(nt * 64 + lane) * 8 + j] = (_Float16)fabsf(v);
        }
    }
}

// ---- one block per batch element, now 8 waves/block ----
// r14 theory: VALU-issue-bound (VALUBusy 67%) at only 4 waves/SIMD (grid-capped
// 1024 blocks x 4 waves = 16 waves/CU). 512 threads/block doubles resident TLP
// to 8 waves/SIMD (LDS 29KB x 4 blocks/CU fits 160KB; launch_bounds(512,8)
// keeps the proven 64-VGPR allocation) -> VALUBusy toward ~90%, same inst count.
__global__ __launch_bounds__(512, 8) void fused_net(
    const float* __restrict__ x, const float* __restrict__ w0,
    const _Float16* __restrict__ bsigG, const _Float16* __restrict__ babsG,
    const unsigned long long* __restrict__ wb1, const unsigned long long* __restrict__ wb2,
    const unsigned long long* __restrict__ wb3, const unsigned long long* __restrict__ wb4,
    const float* __restrict__ w5, float* __restrict__ out) {
    __shared__ _Float16 xh[3172];              // image f16; row stride 33, chan stride 1057
    __shared__ uint4 bfrag[512];               // B sign-fragments (8 KB)
    __shared__ uint4 bfraga[512];              // |B| fragments (8 KB)
    __shared__ alignas(16) unsigned long long bits1[450];  // [15*15][2]
    __shared__ alignas(16) unsigned long long bits2[72];
    __shared__ unsigned long long bits3[18];
    __shared__ unsigned long long bits4[2];
    __shared__ float r_s[128];
    __shared__ float l_s[NUM_CLS];
    __shared__ float e_s[NUM_CLS];
    __shared__ unsigned int qcnt;
    __shared__ unsigned int queue[256];

    int b = blockIdx.x;
    int tid = threadIdx.x;
    int lane = tid & 63, wave = tid >> 6;      // wave in 0..7
    const float* xb = x + (size_t)b * 3072;

    // ================= phase 0: conv0 via f16 MFMA (pool-ordered im2col) =================
    {
        for (int i = tid; i < 3072; i += 512) {
            int c = i >> 10, rem = i & 1023;
            xh[c * 1057 + (rem >> 5) * 33 + (rem & 31)] = (_Float16)xb[i];  // cvt at staging
        }
        const uint4* bs4 = (const uint4*)bsigG;
        const uint4* ba4 = (const uint4*)babsG;
        for (int i = tid; i < 512; i += 512) { bfrag[i] = bs4[i]; bfraga[i] = ba4[i]; }
        if (tid == 0) qcnt = 0;

        int k0 = (lane >> 4) * 8;
        int offj[8];
#pragma unroll
        for (int j = 0; j < 8; j++) {
            int k = k0 + j;
            int c = k / 9, r = (k % 9) / 3, q = k % 3;
            offj[j] = c * 1057 + r * 33 + q;
        }
        unsigned short* b1u16 = (unsigned short*)bits1;
        __syncthreads();

        for (int mt = wave; mt < 57; mt += 8) {   // M = 225*4 = 900 -> 57 tiles / 8 waves
            int mg = mt * 16 + (lane & 15);
            int me = mg < 900 ? mg : 899;
            int p = me >> 2, win = me & 3;
            int py = p / 15, px = p - py * 15;
            int base = (py * 2 + (win >> 1)) * 33 + px * 2 + (win & 1);
            v8h a;
#pragma unroll
            for (int j = 0; j < 8; j++)
                a[j] = (k0 + j < 27) ? xh[base + offj[j]] : (_Float16)0.f;
            HU ua; ua.h = a;                      // |A| for the error-bound MFMA
            ua.u.x &= 0x7FFF7FFFu; ua.u.y &= 0x7FFF7FFFu;
            ua.u.z &= 0x7FFF7FFFu; ua.u.w &= 0x7FFF7FFFu;
            int myp = mt * 4 + (lane >> 4);
#pragma unroll
            for (int nt = 0; nt < 8; nt++) {
                HU bs; bs.u = bfrag[nt * 64 + lane];
                HU ba; ba.u = bfraga[nt * 64 + lane];
                v4f s  = __builtin_amdgcn_mfma_f32_16x16x32_f16(a,    bs.h, (v4f){0.f,0.f,0.f,0.f}, 0, 0, 0);
                v4f sa = __builtin_amdgcn_mfma_f32_16x16x32_f16(ua.h, ba.h, (v4f){0.f,0.f,0.f,0.f}, 0, 0, 0);
                // rigorous f16-rounding bounds; sign logic as wave-mask ballots
                float bd0 = fmaf(sa[0], 1.1e-3f, 1e-5f);
                float bd1 = fmaf(sa[1], 1.1e-3f, 1e-5f);
                float bd2 = fmaf(sa[2], 1.1e-3f, 1e-5f);
                float bd3 = fmaf(sa[3], 1.1e-3f, 1e-5f);
                unsigned long long mkpos =
                    __ballot(s[0] >= bd0) | __ballot(s[1] >= bd1) |
                    __ballot(s[2] >= bd2) | __ballot(s[3] >= bd3);
                unsigned long long mkunc =
                    (__ballot(fabsf(s[0]) < bd0) | __ballot(fabsf(s[1]) < bd1) |
                     __ballot(fabsf(s[2]) < bd2) | __ballot(fabsf(s[3]) < bd3)) & ~mkpos;
                if ((lane & 15) == 0 && myp < 225)
                    b1u16[myp * 8 + nt] = (unsigned short)(mkpos >> (lane & 48));
                if (__builtin_expect(mkunc != 0ull, 0)) {
                    if (((mkunc >> lane) & 1ull) && myp < 225) {
                        unsigned int qi = atomicAdd(&qcnt, 1u);
                        if (qi < 256) queue[qi] = (unsigned)myp | ((unsigned)(nt * 16 + (lane & 15)) << 8);
                    }
                }
            }
        }
        __syncthreads();
        // ---- drain queue: exact f64 signs from GLOBAL f32 x (rare; all 4 windows) ----
        unsigned int nq = qcnt < 256u ? qcnt : 256u;
        for (unsigned int i = tid; i < nq; i += 512) {
            unsigned int e = queue[i];
            int p = e & 255; int oc = (e >> 8) & 255;
            int py = p / 15, px = p - py * 15;
            bool pos = false;
#pragma unroll
            for (int win = 0; win < 4; win++) {
                int base = (py * 2 + (win >> 1)) * 32 + px * 2 + (win & 1);
                double sd = 0.0;
#pragma unroll
                for (int k = 0; k < 27; k++) {
                    int c = k / 9, r = (k % 9) / 3, q = k % 3;
                    sd += (double)xb[base + c * 1024 + r * 32 + q] * (double)w0[oc * 27 + k];
                }
                pos |= (sd >= 0.0);
            }
            if (pos) atomicOr(&bits1[p * 2 + (oc >> 6)], 1ull << (oc & 63));
        }
    }
    __syncthreads();

    int wave2 = tid >> 6, half = wave2 & 1, pair = wave2 >> 1;   // pair in 0..3
    int oc = half * 64 + lane;

    // ================= phase 1: binconv1 (15->13) + maxpool2 (->6) =================
    {
        unsigned long long wr[18];
#pragma unroll
        for (int j = 0; j < 18; j++) wr[j] = wb1[oc * 18 + j];
        const ulonglong2* b1v = (const ulonglong2*)bits1;
        for (int p = pair; p < 36; p += 4) {
            int py = p / 6, px = p % 6;
            int P0 = 0, P1 = 0, P2 = 0, P3 = 0;
#pragma unroll
            for (int yy = 0; yy < 4; yy++) {
                int rb = (2 * py + yy) * 15 + 2 * px;
                ulonglong2 q0 = b1v[rb];
                ulonglong2 q1 = b1v[rb + 1];
                ulonglong2 q2 = b1v[rb + 2];
                ulonglong2 q3 = b1v[rb + 3];
#pragma unroll
                for (int dy = 0; dy < 2; dy++) {
                    int ky = yy - dy;
                    if (ky < 0 || ky > 2) continue;
#pragma unroll
                    for (int kx = 0; kx < 3; kx++) {
                        ulonglong2 qa = kx == 0 ? q0 : (kx == 1 ? q1 : q2);
                        ulonglong2 qb = kx == 0 ? q1 : (kx == 1 ? q2 : q3);
                        int d0 = __popcll(qa.x ^ wr[(ky * 3 + kx) * 2]) +
                                 __popcll(qa.y ^ wr[(ky * 3 + kx) * 2 + 1]);
                        int d1 = __popcll(qb.x ^ wr[(ky * 3 + kx) * 2]) +
                                 __popcll(qb.y ^ wr[(ky * 3 + kx) * 2 + 1]);
                        if (dy == 0) { P0 += d0; P1 += d1; }
                        else         { P2 += d0; P3 += d1; }
                    }
                }
            }
            unsigned long long m = __ballot(P0 <= 576) | __ballot(P1 <= 576) |
                                   __ballot(P2 <= 576) | __ballot(P3 <= 576);
            if (lane == 0) bits2[p * 2 + half] = m;
        }
    }
    __syncthreads();

    // ================= phase 2: binconv2 (6->4) + maxpool(2,s1) (->3) =================
    {
        unsigned long long wr[18];
#pragma unroll
        for (int j = 0; j < 18; j++) wr[j] = wb2[oc * 18 + j];
        const ulonglong2* b2v = (const ulonglong2*)bits2;
        for (int p = pair; p < 9; p += 4) {
            int py = p / 3, px = p % 3;
            int P4[4];
#pragma unroll
            for (int dy = 0; dy < 2; dy++)
#pragma unroll
                for (int dx = 0; dx < 2; dx++) {
                    int P = 0;
#pragma unroll
                    for (int ky = 0; ky < 3; ky++)
#pragma unroll
                        for (int kx = 0; kx < 3; kx++) {
                            ulonglong2 q = b2v[(py + dy + ky) * 6 + (px + dx + kx)];
                            P += __popcll(q.x ^ wr[(ky * 3 + kx) * 2]);
                            P += __popcll(q.y ^ wr[(ky * 3 + kx) * 2 + 1]);
                        }
                    P4[dy * 2 + dx] = P;
                }
            unsigned long long m = __ballot(P4[0] <= 576) | __ballot(P4[1] <= 576) |
                                   __ballot(P4[2] <= 576) | __ballot(P4[3] <= 576);
            if (lane == 0) bits3[p * 2 + half] = m;
        }
    }
    __syncthreads();

    // ================= phase 3: binconv3 + binconv4 + relu + w5 + softmax =================
    if (tid < 128) {
        int P = 0;
#pragma unroll
        for (int k = 0; k < 9; k++) {
            P += __popcll(bits3[k * 2] ^ wb3[tid * 18 + k * 2]);
            P += __popcll(bits3[k * 2 + 1] ^ wb3[tid * 18 + k * 2 + 1]);
        }
        unsigned long long m = __ballot(P <= 576);
        if ((tid & 63) == 0) bits4[tid >> 6] = m;
    }
    __syncthreads();
    if (tid < 128) {
        unsigned long long i0 = bits4[0], i1 = bits4[1];
        int v = 128 - 2 * (int)(__popcll(i0 ^ wb4[tid * 2]) + __popcll(i1 ^ wb4[tid * 2 + 1]));
        r_s[tid] = v > 0 ? (float)v : 0.f;   // relu
    }
    __syncthreads();
    if (tid < NUM_CLS) {
        float l = 0.f;
#pragma unroll 8
        for (int k = 0; k < 128; k++) l = fmaf(w5[tid * 128 + k], r_s[k], l);
        l_s[tid] = l;
    }
    __syncthreads();
    if (tid < NUM_CLS) {
        float mx = -1e30f;
        for (int k = 0; k < NUM_CLS; k++) mx = fmaxf(mx, l_s[k]);
        e_s[tid] = expf(l_s[tid] - mx);
    }
    __syncthreads();
    if (tid < NUM_CLS) {
        float sum = 0.f;
        for (int k = 0; k < NUM_CLS; k++) sum += e_s[k];
        out[(size_t)b * NUM_CLS + tid] = e_s[tid] / sum;
    }
}

extern "C" void kernel_launch(void* const* d_in, const int* in_sizes, int n_in,
                              void* d_out, int out_size, void* d_ws, size_t ws_size,
                              hipStream_t stream) {
    const float* x  = (const float*)d_in[0];
    const float* w0 = (const float*)d_in[1];
    const float* w1 = (const float*)d_in[2];
    const float* w2 = (const float*)d_in[3];
    const float* w3 = (const float*)d_in[4];
    const float* w4 = (const float*)d_in[5];
    const float* w5 = (const float*)d_in[6];
    float* out = (float*)d_out;

    int B = in_sizes[0] / 3072;   // 1024

    size_t off = 0;
    auto carve = [&](size_t bytes) {
        void* p = (char*)d_ws + off;
        off += (bytes + 255) & ~(size_t)255;
        return p;
    };
    unsigned long long* wb1 = (unsigned long long*)carve(1152 * 2 * 8);
    unsigned long long* wb2 = (unsigned long long*)carve(1152 * 2 * 8);
    unsigned long long* wb3 = (unsigned long long*)carve(1152 * 2 * 8);
    unsigned long long* wb4 = (unsigned long long*)carve(128 * 2 * 8);
    _Float16* bsig = (_Float16*)carve(8 * 64 * 8 * 2);   // MFMA B-frags (signed)
    _Float16* babs = (_Float16*)carve(8 * 64 * 8 * 2);   // MFMA B-frags (abs)
    (void)ws_size; (void)n_in; (void)out_size;

    prep_all<<<418, 256, 0, stream>>>(w0, w1, w2, w3, w4, wb1, wb2, wb3, wb4, bsig, babs);
    fused_net<<<B, 512, 0, stream>>>(x, w0, bsig, babs, wb1, wb2, wb3, wb4, w5, out);
}

// Round 2
// 221.940 us; speedup vs baseline: 1.3342x; 1.3342x over previous
//
#include <hip/hip_runtime.h>
#include <cmath>

#define NUM_CLS 58

typedef _Float16 v8h __attribute__((ext_vector_type(8)));
typedef float v4f __attribute__((ext_vector_type(4)));
union HU { v8h h; uint4 u; };

// ---------------- prep v3: 256-thread blocks, coalesced staging ----------------
// blocks 0..383   : per-oc binarize of w1/w2/w3 (layer=id>>7, oc=id&127)
// blocks 384..415 : w4 binarize (1 oc per wave)
// blocks 416..417 : w0 MFMA B-fragments, signed + abs (4 nt per block)
__global__ __launch_bounds__(256) void prep_all(
    const float* __restrict__ w0, const float* __restrict__ w1,
    const float* __restrict__ w2, const float* __restrict__ w3,
    const float* __restrict__ w4,
    unsigned long long* __restrict__ wb1, unsigned long long* __restrict__ wb2,
    unsigned long long* __restrict__ wb3, unsigned long long* __restrict__ wb4,
    _Float16* __restrict__ bsig, _Float16* __restrict__ babs) {
    int id = blockIdx.x, tid = threadIdx.x;
    int lane = tid & 63, wv = tid >> 6;
    if (id < 384) {
        int layer = id >> 7, oc = id & 127;
        const float* w = layer == 0 ? w1 : (layer == 1 ? w2 : w3);
        unsigned long long* o = layer == 0 ? wb1 : (layer == 1 ? wb2 : wb3);
        __shared__ float s[1152];
        const float* base = w + (size_t)oc * 1152;
        for (int i = tid; i < 1152; i += 256) s[i] = base[i];   // coalesced
        __syncthreads();
        for (int k = wv; k < 9; k += 4) {    // stride-9 LDS reads: 2-way banks, free
            unsigned long long b0 = __ballot(s[lane * 9 + k] >= 0.f);
            unsigned long long b1 = __ballot(s[(lane + 64) * 9 + k] >= 0.f);
            if (lane == 0) { o[(oc * 9 + k) * 2] = b0; o[(oc * 9 + k) * 2 + 1] = b1; }
        }
    } else if (id < 416) {
        int oc = (id - 384) * 4 + wv;        // 128 oc over 32 blocks x 4 waves
        unsigned long long b0 = __ballot(w4[oc * 128 + lane] >= 0.f);
        unsigned long long b1 = __ballot(w4[oc * 128 + lane + 64] >= 0.f);
        if (lane == 0) { wb4[oc * 2] = b0; wb4[oc * 2 + 1] = b1; }
    } else {
        int nt = (id - 416) * 4 + wv;        // 8 nt over 2 blocks x 4 waves
        int n = nt * 16 + (lane & 15);
        int k0 = (lane >> 4) * 8;
#pragma unroll
        for (int j = 0; j < 8; j++) {
            int k = k0 + j;
            float v = (k < 27) ? w0[n * 27 + k] : 0.f;
            bsig[(nt * 64 + lane) * 8 + j] = (_Float16)v;
            babs[(nt * 64 + lane) * 8 + j] = (_Float16)fabsf(v);
        }
    }
}

// ---- one block per batch element, 6 waves/block ----
// r14: VALU-issue-bound (VALUBusy 67%) at 4 waves/SIMD (grid-capped).
// r15 POST-MORTEM: (512,8) capped unified regs at 64/wave -> allocator halved
// arch VGPRs to 32 and spilled ~700 MB/dispatch to scratch (FETCH 449 MB). This
// kernel NEEDS 64 VGPRs. (384,6) caps at 512/6=85 > 64 -> no spill, and gives
// 5 blocks/CU (wave-slot 32/6; LDS 29K*5=146K<160K) => 24 waves/CU resident
// (all 1024 blocks co-resident), 1.5x baseline TLP.
__global__ __launch_bounds__(384, 6) void fused_net(
    const float* __restrict__ x, const float* __restrict__ w0,
    const _Float16* __restrict__ bsigG, const _Float16* __restrict__ babsG,
    const unsigned long long* __restrict__ wb1, const unsigned long long* __restrict__ wb2,
    const unsigned long long* __restrict__ wb3, const unsigned long long* __restrict__ wb4,
    const float* __restrict__ w5, float* __restrict__ out) {
    __shared__ _Float16 xh[3172];              // image f16; row stride 33, chan stride 1057
    __shared__ uint4 bfrag[512];               // B sign-fragments (8 KB)
    __shared__ uint4 bfraga[512];              // |B| fragments (8 KB)
    __shared__ alignas(16) unsigned long long bits1[450];  // [15*15][2]
    __shared__ alignas(16) unsigned long long bits2[72];
    __shared__ unsigned long long bits3[18];
    __shared__ unsigned long long bits4[2];
    __shared__ float r_s[128];
    __shared__ float l_s[NUM_CLS];
    __shared__ float e_s[NUM_CLS];
    __shared__ unsigned int qcnt;
    __shared__ unsigned int queue[256];

    int b = blockIdx.x;
    int tid = threadIdx.x;
    int lane = tid & 63, wave = tid >> 6;      // wave in 0..5
    const float* xb = x + (size_t)b * 3072;

    // ================= phase 0: conv0 via f16 MFMA (pool-ordered im2col) =================
    {
        for (int i = tid; i < 3072; i += 384) {
            int c = i >> 10, rem = i & 1023;
            xh[c * 1057 + (rem >> 5) * 33 + (rem & 31)] = (_Float16)xb[i];  // cvt at staging
        }
        const uint4* bs4 = (const uint4*)bsigG;
        const uint4* ba4 = (const uint4*)babsG;
        for (int i = tid; i < 512; i += 384) { bfrag[i] = bs4[i]; bfraga[i] = ba4[i]; }
        if (tid == 0) qcnt = 0;

        int k0 = (lane >> 4) * 8;
        int offj[8];
#pragma unroll
        for (int j = 0; j < 8; j++) {
            int k = k0 + j;
            int c = k / 9, r = (k % 9) / 3, q = k % 3;
            offj[j] = c * 1057 + r * 33 + q;
        }
        unsigned short* b1u16 = (unsigned short*)bits1;
        __syncthreads();

        for (int mt = wave; mt < 57; mt += 6) {   // M = 225*4 = 900 -> 57 tiles / 6 waves
            int mg = mt * 16 + (lane & 15);
            int me = mg < 900 ? mg : 899;
            int p = me >> 2, win = me & 3;
            int py = p / 15, px = p - py * 15;
            int base = (py * 2 + (win >> 1)) * 33 + px * 2 + (win & 1);
            v8h a;
#pragma unroll
            for (int j = 0; j < 8; j++)
                a[j] = (k0 + j < 27) ? xh[base + offj[j]] : (_Float16)0.f;
            HU ua; ua.h = a;                      // |A| for the error-bound MFMA
            ua.u.x &= 0x7FFF7FFFu; ua.u.y &= 0x7FFF7FFFu;
            ua.u.z &= 0x7FFF7FFFu; ua.u.w &= 0x7FFF7FFFu;
            int myp = mt * 4 + (lane >> 4);
#pragma unroll
            for (int nt = 0; nt < 8; nt++) {
                HU bs; bs.u = bfrag[nt * 64 + lane];
                HU ba; ba.u = bfraga[nt * 64 + lane];
                v4f s  = __builtin_amdgcn_mfma_f32_16x16x32_f16(a,    bs.h, (v4f){0.f,0.f,0.f,0.f}, 0, 0, 0);
                v4f sa = __builtin_amdgcn_mfma_f32_16x16x32_f16(ua.h, ba.h, (v4f){0.f,0.f,0.f,0.f}, 0, 0, 0);
                // rigorous f16-rounding bounds; sign logic as wave-mask ballots
                float bd0 = fmaf(sa[0], 1.1e-3f, 1e-5f);
                float bd1 = fmaf(sa[1], 1.1e-3f, 1e-5f);
                float bd2 = fmaf(sa[2], 1.1e-3f, 1e-5f);
                float bd3 = fmaf(sa[3], 1.1e-3f, 1e-5f);
                unsigned long long mkpos =
                    __ballot(s[0] >= bd0) | __ballot(s[1] >= bd1) |
                    __ballot(s[2] >= bd2) | __ballot(s[3] >= bd3);
                unsigned long long mkunc =
                    (__ballot(fabsf(s[0]) < bd0) | __ballot(fabsf(s[1]) < bd1) |
                     __ballot(fabsf(s[2]) < bd2) | __ballot(fabsf(s[3]) < bd3)) & ~mkpos;
                if ((lane & 15) == 0 && myp < 225)
                    b1u16[myp * 8 + nt] = (unsigned short)(mkpos >> (lane & 48));
                if (__builtin_expect(mkunc != 0ull, 0)) {
                    if (((mkunc >> lane) & 1ull) && myp < 225) {
                        unsigned int qi = atomicAdd(&qcnt, 1u);
                        if (qi < 256) queue[qi] = (unsigned)myp | ((unsigned)(nt * 16 + (lane & 15)) << 8);
                    }
                }
            }
        }
        __syncthreads();
        // ---- drain queue: exact f64 signs from GLOBAL f32 x (rare; all 4 windows) ----
        unsigned int nq = qcnt < 256u ? qcnt : 256u;
        for (unsigned int i = tid; i < nq; i += 384) {
            unsigned int e = queue[i];
            int p = e & 255; int oc = (e >> 8) & 255;
            int py = p / 15, px = p - py * 15;
            bool pos = false;
#pragma unroll
            for (int win = 0; win < 4; win++) {
                int base = (py * 2 + (win >> 1)) * 32 + px * 2 + (win & 1);
                double sd = 0.0;
#pragma unroll
                for (int k = 0; k < 27; k++) {
                    int c = k / 9, r = (k % 9) / 3, q = k % 3;
                    sd += (double)xb[base + c * 1024 + r * 32 + q] * (double)w0[oc * 27 + k];
                }
                pos |= (sd >= 0.0);
            }
            if (pos) atomicOr(&bits1[p * 2 + (oc >> 6)], 1ull << (oc & 63));
        }
    }
    __syncthreads();

    int wave2 = tid >> 6, half = wave2 & 1, pair = wave2 >> 1;   // pair in 0..2
    int oc = half * 64 + lane;

    // ================= phase 1: binconv1 (15->13) + maxpool2 (->6) =================
    {
        unsigned long long wr[18];
#pragma unroll
        for (int j = 0; j < 18; j++) wr[j] = wb1[oc * 18 + j];
        const ulonglong2* b1v = (const ulonglong2*)bits1;
        for (int p = pair; p < 36; p += 3) {
            int py = p / 6, px = p % 6;
            int P0 = 0, P1 = 0, P2 = 0, P3 = 0;
#pragma unroll
            for (int yy = 0; yy < 4; yy++) {
                int rb = (2 * py + yy) * 15 + 2 * px;
                ulonglong2 q0 = b1v[rb];
                ulonglong2 q1 = b1v[rb + 1];
                ulonglong2 q2 = b1v[rb + 2];
                ulonglong2 q3 = b1v[rb + 3];
#pragma unroll
                for (int dy = 0; dy < 2; dy++) {
                    int ky = yy - dy;
                    if (ky < 0 || ky > 2) continue;
#pragma unroll
                    for (int kx = 0; kx < 3; kx++) {
                        ulonglong2 qa = kx == 0 ? q0 : (kx == 1 ? q1 : q2);
                        ulonglong2 qb = kx == 0 ? q1 : (kx == 1 ? q2 : q3);
                        int d0 = __popcll(qa.x ^ wr[(ky * 3 + kx) * 2]) +
                                 __popcll(qa.y ^ wr[(ky * 3 + kx) * 2 + 1]);
                        int d1 = __popcll(qb.x ^ wr[(ky * 3 + kx) * 2]) +
                                 __popcll(qb.y ^ wr[(ky * 3 + kx) * 2 + 1]);
                        if (dy == 0) { P0 += d0; P1 += d1; }
                        else         { P2 += d0; P3 += d1; }
                    }
                }
            }
            unsigned long long m = __ballot(P0 <= 576) | __ballot(P1 <= 576) |
                                   __ballot(P2 <= 576) | __ballot(P3 <= 576);
            if (lane == 0) bits2[p * 2 + half] = m;
        }
    }
    __syncthreads();

    // ================= phase 2: binconv2 (6->4) + maxpool(2,s1) (->3) =================
    {
        unsigned long long wr[18];
#pragma unroll
        for (int j = 0; j < 18; j++) wr[j] = wb2[oc * 18 + j];
        const ulonglong2* b2v = (const ulonglong2*)bits2;
        for (int p = pair; p < 9; p += 3) {
            int py = p / 3, px = p % 3;
            int P4[4];
#pragma unroll
            for (int dy = 0; dy < 2; dy++)
#pragma unroll
                for (int dx = 0; dx < 2; dx++) {
                    int P = 0;
#pragma unroll
                    for (int ky = 0; ky < 3; ky++)
#pragma unroll
                        for (int kx = 0; kx < 3; kx++) {
                            ulonglong2 q = b2v[(py + dy + ky) * 6 + (px + dx + kx)];
                            P += __popcll(q.x ^ wr[(ky * 3 + kx) * 2]);
                            P += __popcll(q.y ^ wr[(ky * 3 + kx) * 2 + 1]);
                        }
                    P4[dy * 2 + dx] = P;
                }
            unsigned long long m = __ballot(P4[0] <= 576) | __ballot(P4[1] <= 576) |
                                   __ballot(P4[2] <= 576) | __ballot(P4[3] <= 576);
            if (lane == 0) bits3[p * 2 + half] = m;
        }
    }
    __syncthreads();

    // ================= phase 3: binconv3 + binconv4 + relu + w5 + softmax =================
    if (tid < 128) {
        int P = 0;
#pragma unroll
        for (int k = 0; k < 9; k++) {
            P += __popcll(bits3[k * 2] ^ wb3[tid * 18 + k * 2]);
            P += __popcll(bits3[k * 2 + 1] ^ wb3[tid * 18 + k * 2 + 1]);
        }
        unsigned long long m = __ballot(P <= 576);
        if ((tid & 63) == 0) bits4[tid >> 6] = m;
    }
    __syncthreads();
    if (tid < 128) {
        unsigned long long i0 = bits4[0], i1 = bits4[1];
        int v = 128 - 2 * (int)(__popcll(i0 ^ wb4[tid * 2]) + __popcll(i1 ^ wb4[tid * 2 + 1]));
        r_s[tid] = v > 0 ? (float)v : 0.f;   // relu
    }
    __syncthreads();
    if (tid < NUM_CLS) {
        float l = 0.f;
#pragma unroll 8
        for (int k = 0; k < 128; k++) l = fmaf(w5[tid * 128 + k], r_s[k], l);
        l_s[tid] = l;
    }
    __syncthreads();
    if (tid < NUM_CLS) {
        float mx = -1e30f;
        for (int k = 0; k < NUM_CLS; k++) mx = fmaxf(mx, l_s[k]);
        e_s[tid] = expf(l_s[tid] - mx);
    }
    __syncthreads();
    if (tid < NUM_CLS) {
        float sum = 0.f;
        for (int k = 0; k < NUM_CLS; k++) sum += e_s[k];
        out[(size_t)b * NUM_CLS + tid] = e_s[tid] / sum;
    }
}

extern "C" void kernel_launch(void* const* d_in, const int* in_sizes, int n_in,
                              void* d_out, int out_size, void* d_ws, size_t ws_size,
                              hipStream_t stream) {
    const float* x  = (const float*)d_in[0];
    const float* w0 = (const float*)d_in[1];
    const float* w1 = (const float*)d_in[2];
    const float* w2 = (const float*)d_in[3];
    const float* w3 = (const float*)d_in[4];
    const float* w4 = (const float*)d_in[5];
    const float* w5 = (const float*)d_in[6];
    float* out = (float*)d_out;

    int B = in_sizes[0] / 3072;   // 1024

    size_t off = 0;
    auto carve = [&](size_t bytes) {
        void* p = (char*)d_ws + off;
        off += (bytes + 255) & ~(size_t)255;
        return p;
    };
    unsigned long long* wb1 = (unsigned long long*)carve(1152 * 2 * 8);
    unsigned long long* wb2 = (unsigned long long*)carve(1152 * 2 * 8);
    unsigned long long* wb3 = (unsigned long long*)carve(1152 * 2 * 8);
    unsigned long long* wb4 = (unsigned long long*)carve(128 * 2 * 8);
    _Float16* bsig = (_Float16*)carve(8 * 64 * 8 * 2);   // MFMA B-frags (signed)
    _Float16* babs = (_Float16*)carve(8 * 64 * 8 * 2);   // MFMA B-frags (abs)
    (void)ws_size; (void)n_in; (void)out_size;

    prep_all<<<418, 256, 0, stream>>>(w0, w1, w2, w3, w4, wb1, wb2, wb3, wb4, bsig, babs);
    fused_net<<<B, 384, 0, stream>>>(x, w0, bsig, babs, wb1, wb2, wb3, wb4, w5, out);
}

// Round 3
// 160.499 us; speedup vs baseline: 1.8449x; 1.3828x over previous
//
#include <hip/hip_runtime.h>
#include <cmath>

#define NUM_CLS 58

typedef _Float16 v8h __attribute__((ext_vector_type(8)));
typedef float v4f __attribute__((ext_vector_type(4)));
union HU { v8h h; uint4 u; };

// ---------------- prep v3: 256-thread blocks, coalesced staging ----------------
// blocks 0..383   : per-oc binarize of w1/w2/w3 (layer=id>>7, oc=id&127)
// blocks 384..415 : w4 binarize (1 oc per wave)
// blocks 416..417 : w0 MFMA B-fragments, signed + abs (4 nt per block)
__global__ __launch_bounds__(256) void prep_all(
    const float* __restrict__ w0, const float* __restrict__ w1,
    const float* __restrict__ w2, const float* __restrict__ w3,
    const float* __restrict__ w4,
    unsigned long long* __restrict__ wb1, unsigned long long* __restrict__ wb2,
    unsigned long long* __restrict__ wb3, unsigned long long* __restrict__ wb4,
    _Float16* __restrict__ bsig, _Float16* __restrict__ babs) {
    int id = blockIdx.x, tid = threadIdx.x;
    int lane = tid & 63, wv = tid >> 6;
    if (id < 384) {
        int layer = id >> 7, oc = id & 127;
        const float* w = layer == 0 ? w1 : (layer == 1 ? w2 : w3);
        unsigned long long* o = layer == 0 ? wb1 : (layer == 1 ? wb2 : wb3);
        __shared__ float s[1152];
        const float* base = w + (size_t)oc * 1152;
        for (int i = tid; i < 1152; i += 256) s[i] = base[i];   // coalesced
        __syncthreads();
        for (int k = wv; k < 9; k += 4) {    // stride-9 LDS reads: 2-way banks, free
            unsigned long long b0 = __ballot(s[lane * 9 + k] >= 0.f);
            unsigned long long b1 = __ballot(s[(lane + 64) * 9 + k] >= 0.f);
            if (lane == 0) { o[(oc * 9 + k) * 2] = b0; o[(oc * 9 + k) * 2 + 1] = b1; }
        }
    } else if (id < 416) {
        int oc = (id - 384) * 4 + wv;        // 128 oc over 32 blocks x 4 waves
        unsigned long long b0 = __ballot(w4[oc * 128 + lane] >= 0.f);
        unsigned long long b1 = __ballot(w4[oc * 128 + lane + 64] >= 0.f);
        if (lane == 0) { wb4[oc * 2] = b0; wb4[oc * 2 + 1] = b1; }
    } else {
        int nt = (id - 416) * 4 + wv;        // 8 nt over 2 blocks x 4 waves
        int n = nt * 16 + (lane & 15);
        int k0 = (lane >> 4) * 8;
#pragma unroll
        for (int j = 0; j < 8; j++) {
            int k = k0 + j;
            float v = (k < 27) ? w0[n * 27 + k] : 0.f;   // B zero-padded for k>=27
            bsig[(nt * 64 + lane) * 8 + j] = (_Float16)v;
            babs[(nt * 64 + lane) * 8 + j] = (_Float16)fabsf(v);
        }
    }
}

// ---- one block per batch element, 4 waves (REGISTER WALL, measured r1/r2) ----
// Occupancy ladder is CLOSED: __launch_bounds__ min-waves>4 caps unified regs
// at 512/w; compiler splits arch/acc ~50/50 (measured: cap128->64arch,
// cap85->40arch, cap64->32arch) and this kernel needs ~64 arch (wr[18]=36).
// (384,6): 131MB spill, 160us. (512,8): 449MB spill, 235us. (256,4): 64 VGPR,
// no spill, 100us. Grid 1024 = exactly 4 blocks/CU anyway.
// r3 change: A-frag tail (k>=27) loads unconditional — B-frags are zero there
// (prep zero-pads), so A only needs FINITE values; clamp offj to k=26 instead
// of 8 per-lane v_cndmask per m-tile. Also keeps reads inside xh.
__global__ __launch_bounds__(256, 4) void fused_net(
    const float* __restrict__ x, const float* __restrict__ w0,
    const _Float16* __restrict__ bsigG, const _Float16* __restrict__ babsG,
    const unsigned long long* __restrict__ wb1, const unsigned long long* __restrict__ wb2,
    const unsigned long long* __restrict__ wb3, const unsigned long long* __restrict__ wb4,
    const float* __restrict__ w5, float* __restrict__ out) {
    __shared__ _Float16 xh[3172];              // image f16; row stride 33, chan stride 1057
    __shared__ uint4 bfrag[512];               // B sign-fragments (8 KB)
    __shared__ uint4 bfraga[512];              // |B| fragments (8 KB)
    __shared__ alignas(16) unsigned long long bits1[450];  // [15*15][2]
    __shared__ alignas(16) unsigned long long bits2[72];
    __shared__ unsigned long long bits3[18];
    __shared__ unsigned long long bits4[2];
    __shared__ float r_s[128];
    __shared__ float l_s[NUM_CLS];
    __shared__ float e_s[NUM_CLS];
    __shared__ unsigned int qcnt;
    __shared__ unsigned int queue[256];

    int b = blockIdx.x;
    int tid = threadIdx.x;
    int lane = tid & 63, wave = tid >> 6;
    const float* xb = x + (size_t)b * 3072;

    // ================= phase 0: conv0 via f16 MFMA (pool-ordered im2col) =================
    {
        for (int i = tid; i < 3072; i += 256) {
            int c = i >> 10, rem = i & 1023;
            xh[c * 1057 + (rem >> 5) * 33 + (rem & 31)] = (_Float16)xb[i];  // cvt at staging
        }
        const uint4* bs4 = (const uint4*)bsigG;
        const uint4* ba4 = (const uint4*)babsG;
        for (int i = tid; i < 512; i += 256) { bfrag[i] = bs4[i]; bfraga[i] = ba4[i]; }
        if (tid == 0) qcnt = 0;

        int k0 = (lane >> 4) * 8;
        int offj[8];
#pragma unroll
        for (int j = 0; j < 8; j++) {
            int k = k0 + j;
            int kc = k < 27 ? k : 26;          // clamp: tail reads finite value, B=0 there
            int c = kc / 9, r = (kc % 9) / 3, q = kc % 3;
            offj[j] = c * 1057 + r * 33 + q;
        }
        unsigned short* b1u16 = (unsigned short*)bits1;
        __syncthreads();

        for (int mt = wave; mt < 57; mt += 4) {   // M = 225*4 = 900 -> 57 tiles
            int mg = mt * 16 + (lane & 15);
            int me = mg < 900 ? mg : 899;
            int p = me >> 2, win = me & 3;
            int py = p / 15, px = p - py * 15;
            int base = (py * 2 + (win >> 1)) * 33 + px * 2 + (win & 1);
            v8h a;
#pragma unroll
            for (int j = 0; j < 8; j++)
                a[j] = xh[base + offj[j]];        // unconditional: tail killed by B=0
            HU ua; ua.h = a;                      // |A| for the error-bound MFMA
            ua.u.x &= 0x7FFF7FFFu; ua.u.y &= 0x7FFF7FFFu;
            ua.u.z &= 0x7FFF7FFFu; ua.u.w &= 0x7FFF7FFFu;
            int myp = mt * 4 + (lane >> 4);
#pragma unroll
            for (int nt = 0; nt < 8; nt++) {
                HU bs; bs.u = bfrag[nt * 64 + lane];
                HU ba; ba.u = bfraga[nt * 64 + lane];
                v4f s  = __builtin_amdgcn_mfma_f32_16x16x32_f16(a,    bs.h, (v4f){0.f,0.f,0.f,0.f}, 0, 0, 0);
                v4f sa = __builtin_amdgcn_mfma_f32_16x16x32_f16(ua.h, ba.h, (v4f){0.f,0.f,0.f,0.f}, 0, 0, 0);
                // rigorous f16-rounding bounds; sign logic as wave-mask ballots
                float bd0 = fmaf(sa[0], 1.1e-3f, 1e-5f);
                float bd1 = fmaf(sa[1], 1.1e-3f, 1e-5f);
                float bd2 = fmaf(sa[2], 1.1e-3f, 1e-5f);
                float bd3 = fmaf(sa[3], 1.1e-3f, 1e-5f);
                unsigned long long mkpos =
                    __ballot(s[0] >= bd0) | __ballot(s[1] >= bd1) |
                    __ballot(s[2] >= bd2) | __ballot(s[3] >= bd3);
                unsigned long long mkunc =
                    (__ballot(fabsf(s[0]) < bd0) | __ballot(fabsf(s[1]) < bd1) |
                     __ballot(fabsf(s[2]) < bd2) | __ballot(fabsf(s[3]) < bd3)) & ~mkpos;
                if ((lane & 15) == 0 && myp < 225)
                    b1u16[myp * 8 + nt] = (unsigned short)(mkpos >> (lane & 48));
                if (__builtin_expect(mkunc != 0ull, 0)) {
                    if (((mkunc >> lane) & 1ull) && myp < 225) {
                        unsigned int qi = atomicAdd(&qcnt, 1u);
                        if (qi < 256) queue[qi] = (unsigned)myp | ((unsigned)(nt * 16 + (lane & 15)) << 8);
                    }
                }
            }
        }
        __syncthreads();
        // ---- drain queue: exact f64 signs from GLOBAL f32 x (rare; all 4 windows) ----
        unsigned int nq = qcnt < 256u ? qcnt : 256u;
        for (unsigned int i = tid; i < nq; i += 256) {
            unsigned int e = queue[i];
            int p = e & 255; int oc = (e >> 8) & 255;
            int py = p / 15, px = p - py * 15;
            bool pos = false;
#pragma unroll
            for (int win = 0; win < 4; win++) {
                int base = (py * 2 + (win >> 1)) * 32 + px * 2 + (win & 1);
                double sd = 0.0;
#pragma unroll
                for (int k = 0; k < 27; k++) {
                    int c = k / 9, r = (k % 9) / 3, q = k % 3;
                    sd += (double)xb[base + c * 1024 + r * 32 + q] * (double)w0[oc * 27 + k];
                }
                pos |= (sd >= 0.0);
            }
            if (pos) atomicOr(&bits1[p * 2 + (oc >> 6)], 1ull << (oc & 63));
        }
    }
    __syncthreads();

    int wave2 = tid >> 6, half = wave2 & 1, pair = wave2 >> 1;
    int oc = half * 64 + lane;

    // ================= phase 1: binconv1 (15->13) + maxpool2 (->6) =================
    {
        unsigned long long wr[18];
#pragma unroll
        for (int j = 0; j < 18; j++) wr[j] = wb1[oc * 18 + j];
        const ulonglong2* b1v = (const ulonglong2*)bits1;
        for (int p = pair; p < 36; p += 2) {
            int py = p / 6, px = p % 6;
            int P0 = 0, P1 = 0, P2 = 0, P3 = 0;
#pragma unroll
            for (int yy = 0; yy < 4; yy++) {
                int rb = (2 * py + yy) * 15 + 2 * px;
                ulonglong2 q0 = b1v[rb];
                ulonglong2 q1 = b1v[rb + 1];
                ulonglong2 q2 = b1v[rb + 2];
                ulonglong2 q3 = b1v[rb + 3];
#pragma unroll
                for (int dy = 0; dy < 2; dy++) {
                    int ky = yy - dy;
                    if (ky < 0 || ky > 2) continue;
#pragma unroll
                    for (int kx = 0; kx < 3; kx++) {
                        ulonglong2 qa = kx == 0 ? q0 : (kx == 1 ? q1 : q2);
                        ulonglong2 qb = kx == 0 ? q1 : (kx == 1 ? q2 : q3);
                        int d0 = __popcll(qa.x ^ wr[(ky * 3 + kx) * 2]) +
                                 __popcll(qa.y ^ wr[(ky * 3 + kx) * 2 + 1]);
                        int d1 = __popcll(qb.x ^ wr[(ky * 3 + kx) * 2]) +
                                 __popcll(qb.y ^ wr[(ky * 3 + kx) * 2 + 1]);
                        if (dy == 0) { P0 += d0; P1 += d1; }
                        else         { P2 += d0; P3 += d1; }
                    }
                }
            }
            unsigned long long m = __ballot(P0 <= 576) | __ballot(P1 <= 576) |
                                   __ballot(P2 <= 576) | __ballot(P3 <= 576);
            if (lane == 0) bits2[p * 2 + half] = m;
        }
    }
    __syncthreads();

    // ================= phase 2: binconv2 (6->4) + maxpool(2,s1) (->3) =================
    {
        unsigned long long wr[18];
#pragma unroll
        for (int j = 0; j < 18; j++) wr[j] = wb2[oc * 18 + j];
        const ulonglong2* b2v = (const ulonglong2*)bits2;
        for (int p = pair; p < 9; p += 2) {
            int py = p / 3, px = p % 3;
            int P4[4];
#pragma unroll
            for (int dy = 0; dy < 2; dy++)
#pragma unroll
                for (int dx = 0; dx < 2; dx++) {
                    int P = 0;
#pragma unroll
                    for (int ky = 0; ky < 3; ky++)
#pragma unroll
                        for (int kx = 0; kx < 3; kx++) {
                            ulonglong2 q = b2v[(py + dy + ky) * 6 + (px + dx + kx)];
                            P += __popcll(q.x ^ wr[(ky * 3 + kx) * 2]);
                            P += __popcll(q.y ^ wr[(ky * 3 + kx) * 2 + 1]);
                        }
                    P4[dy * 2 + dx] = P;
                }
            unsigned long long m = __ballot(P4[0] <= 576) | __ballot(P4[1] <= 576) |
                                   __ballot(P4[2] <= 576) | __ballot(P4[3] <= 576);
            if (lane == 0) bits3[p * 2 + half] = m;
        }
    }
    __syncthreads();

    // ================= phase 3: binconv3 + binconv4 + relu + w5 + softmax =================
    if (tid < 128) {
        int P = 0;
#pragma unroll
        for (int k = 0; k < 9; k++) {
            P += __popcll(bits3[k * 2] ^ wb3[tid * 18 + k * 2]);
            P += __popcll(bits3[k * 2 + 1] ^ wb3[tid * 18 + k * 2 + 1]);
        }
        unsigned long long m = __ballot(P <= 576);
        if ((tid & 63) == 0) bits4[tid >> 6] = m;
    }
    __syncthreads();
    if (tid < 128) {
        unsigned long long i0 = bits4[0], i1 = bits4[1];
        int v = 128 - 2 * (int)(__popcll(i0 ^ wb4[tid * 2]) + __popcll(i1 ^ wb4[tid * 2 + 1]));
        r_s[tid] = v > 0 ? (float)v : 0.f;   // relu
    }
    __syncthreads();
    if (tid < NUM_CLS) {
        float l = 0.f;
#pragma unroll 8
        for (int k = 0; k < 128; k++) l = fmaf(w5[tid * 128 + k], r_s[k], l);
        l_s[tid] = l;
    }
    __syncthreads();
    if (tid < NUM_CLS) {
        float mx = -1e30f;
        for (int k = 0; k < NUM_CLS; k++) mx = fmaxf(mx, l_s[k]);
        e_s[tid] = expf(l_s[tid] - mx);
    }
    __syncthreads();
    if (tid < NUM_CLS) {
        float sum = 0.f;
        for (int k = 0; k < NUM_CLS; k++) sum += e_s[k];
        out[(size_t)b * NUM_CLS + tid] = e_s[tid] / sum;
    }
}

extern "C" void kernel_launch(void* const* d_in, const int* in_sizes, int n_in,
                              void* d_out, int out_size, void* d_ws, size_t ws_size,
                              hipStream_t stream) {
    const float* x  = (const float*)d_in[0];
    const float* w0 = (const float*)d_in[1];
    const float* w1 = (const float*)d_in[2];
    const float* w2 = (const float*)d_in[3];
    const float* w3 = (const float*)d_in[4];
    const float* w4 = (const float*)d_in[5];
    const float* w5 = (const float*)d_in[6];
    float* out = (float*)d_out;

    int B = in_sizes[0] / 3072;   // 1024

    size_t off = 0;
    auto carve = [&](size_t bytes) {
        void* p = (char*)d_ws + off;
        off += (bytes + 255) & ~(size_t)255;
        return p;
    };
    unsigned long long* wb1 = (unsigned long long*)carve(1152 * 2 * 8);
    unsigned long long* wb2 = (unsigned long long*)carve(1152 * 2 * 8);
    unsigned long long* wb3 = (unsigned long long*)carve(1152 * 2 * 8);
    unsigned long long* wb4 = (unsigned long long*)carve(128 * 2 * 8);
    _Float16* bsig = (_Float16*)carve(8 * 64 * 8 * 2);   // MFMA B-frags (signed)
    _Float16* babs = (_Float16*)carve(8 * 64 * 8 * 2);   // MFMA B-frags (abs)
    (void)ws_size; (void)n_in; (void)out_size;

    prep_all<<<418, 256, 0, stream>>>(w0, w1, w2, w3, w4, wb1, wb2, wb3, wb4, bsig, babs);
    fused_net<<<B, 256, 0, stream>>>(x, w0, bsig, babs, wb1, wb2, wb3, wb4, w5, out);
}

// Round 4
// 150.244 us; speedup vs baseline: 1.9708x; 1.0683x over previous
//
#include <hip/hip_runtime.h>
#include <cmath>

#define NUM_CLS 58

typedef _Float16 v8h __attribute__((ext_vector_type(8)));
typedef float v4f __attribute__((ext_vector_type(4)));
typedef int v4i __attribute__((ext_vector_type(4)));
union HU { v8h h; uint4 u; };

// ---------------- prep v4 ----------------
// blocks 0..255   : per-oc binarize of w2/w3 (layer=id>>7, oc=id&127)
// blocks 256..287 : w4 binarize (1 oc per wave)
// blocks 288..289 : w0 MFMA B-fragments, signed + abs (4 nt per block)
// blocks 290..325 : w1 -> +-1 i8 MFMA B-fragments [tk=18][nt=8][lane=64][16B]
__global__ __launch_bounds__(256) void prep_all(
    const float* __restrict__ w0, const float* __restrict__ w1,
    const float* __restrict__ w2, const float* __restrict__ w3,
    const float* __restrict__ w4,
    unsigned long long* __restrict__ wb2,
    unsigned long long* __restrict__ wb3, unsigned long long* __restrict__ wb4,
    _Float16* __restrict__ bsig, _Float16* __restrict__ babs,
    uint4* __restrict__ bw1f) {
    int id = blockIdx.x, tid = threadIdx.x;
    int lane = tid & 63, wv = tid >> 6;
    if (id < 256) {
        int layer = id >> 7, oc = id & 127;
        const float* w = layer == 0 ? w2 : w3;
        unsigned long long* o = layer == 0 ? wb2 : wb3;
        __shared__ float s[1152];
        const float* base = w + (size_t)oc * 1152;
        for (int i = tid; i < 1152; i += 256) s[i] = base[i];   // coalesced
        __syncthreads();
        for (int k = wv; k < 9; k += 4) {    // stride-9 LDS reads: 2-way banks, free
            unsigned long long b0 = __ballot(s[lane * 9 + k] >= 0.f);
            unsigned long long b1 = __ballot(s[(lane + 64) * 9 + k] >= 0.f);
            if (lane == 0) { o[(oc * 9 + k) * 2] = b0; o[(oc * 9 + k) * 2 + 1] = b1; }
        }
    } else if (id < 288) {
        int oc = (id - 256) * 4 + wv;        // 128 oc over 32 blocks x 4 waves
        unsigned long long b0 = __ballot(w4[oc * 128 + lane] >= 0.f);
        unsigned long long b1 = __ballot(w4[oc * 128 + lane + 64] >= 0.f);
        if (lane == 0) { wb4[oc * 2] = b0; wb4[oc * 2 + 1] = b1; }
    } else if (id < 290) {
        int nt = (id - 288) * 4 + wv;        // 8 nt over 2 blocks x 4 waves
        int n = nt * 16 + (lane & 15);
        int k0 = (lane >> 4) * 8;
#pragma unroll
        for (int j = 0; j < 8; j++) {
            int k = k0 + j;
            float v = (k < 27) ? w0[n * 27 + k] : 0.f;
            bsig[(nt * 64 + lane) * 8 + j] = (_Float16)v;
            babs[(nt * 64 + lane) * 8 + j] = (_Float16)fabsf(v);
        }
    } else {
        // w1 i8 fragments: frag fi=(tk,nt,ln); byte j = sign(w1[oc=nt*16+(ln&15)]
        //   [ic=kk*64+(ln>>4)*16+j][tap]) as +1/-1 i8. w1 idx = oc*1152 + ic*9 + tap.
        int fi = (id - 290) * 256 + tid;     // 0..9215
        int tk = fi >> 9;                    // 0..17 (tap*2+kk)
        int rem = fi & 511;
        int nt = rem >> 6, ln = rem & 63;
        int oc = nt * 16 + (ln & 15);
        int tap = tk >> 1, kk = tk & 1;
        int icb = kk * 64 + (ln >> 4) * 16;
        const float* wp = w1 + (size_t)oc * 1152 + tap;
        unsigned int dd[4];
#pragma unroll
        for (int q = 0; q < 4; ++q) {
            unsigned int v = 0;
#pragma unroll
            for (int j = 0; j < 4; ++j)
                v |= (wp[(icb + q * 4 + j) * 9] >= 0.f ? 0x01u : 0xFFu) << (8 * j);
            dd[q] = v;
        }
        uint4 d; d.x = dd[0]; d.y = dd[1]; d.z = dd[2]; d.w = dd[3];
        bw1f[fi] = d;
    }
}

// LDS overlays: phase-0 staging set and the phase-1 i8 expansion share one union
// (xh/bfrag/bfraga dead after the post-drain barrier). sgn1 overlays bits1
// (dead after expansion reads it). Total LDS ~38.9 KB -> 4 blocks/CU kept.
union UEXP {
    struct {
        _Float16 xh[3172];                 // image f16; row stride 33, chan stride 1057
        alignas(16) uint4 bfrag[512];      // conv0 B sign-fragments (8 KB)
        uint4 bfraga[512];                 // conv0 |B| fragments (8 KB)
    } p0;
    unsigned char expb[225 * 144];         // +-1 i8 input, [pos][144B stride]
};
union BS {
    alignas(16) unsigned long long bits1[450];  // [15*15][2]
    unsigned short sgn1[144 * 8];               // binconv1 window signs [w][nt]
};

// ---- one block per batch element, 4 waves (REGISTER WALL, measured r1/r2) ----
// Occupancy ladder CLOSED: min-waves>4 caps unified regs at 512/w, compiler
// splits arch/acc ~50/50, this kernel needs ~64 arch -> spills (131-449MB).
// r4: binconv1 popcount (the largest VALU phase, ~26k wave-instrs) replaced by
// EXACT i8 MFMA: C = sum(+-1 * +-1) = 1152-2P, sign identical. 324 MFMA/wave
// on the idle matrix pipe. A: bits1 expanded to +-1 i8 in LDS (stride 144 =
// even 32-bank spread for the 16-row x 4-kgroup b128 reads). B: prep-built
// fragments, L2-resident. C-layout (col=lane&15,row=(lane>>4)*4+r) proven by
// phase-0's working ballot code.
__global__ __launch_bounds__(256, 4) void fused_net(
    const float* __restrict__ x, const float* __restrict__ w0,
    const _Float16* __restrict__ bsigG, const _Float16* __restrict__ babsG,
    const uint4* __restrict__ bw1f, const unsigned long long* __restrict__ wb2,
    const unsigned long long* __restrict__ wb3, const unsigned long long* __restrict__ wb4,
    const float* __restrict__ w5, float* __restrict__ out) {
    __shared__ UEXP u;
    __shared__ BS bs;
    __shared__ unsigned int lut[16];
    __shared__ alignas(16) unsigned long long bits2[72];
    __shared__ unsigned long long bits3[18];
    __shared__ unsigned long long bits4[2];
    __shared__ float r_s[128];
    __shared__ float l_s[NUM_CLS];
    __shared__ float e_s[NUM_CLS];
    __shared__ unsigned int qcnt;
    __shared__ unsigned int queue[256];

    int b = blockIdx.x;
    int tid = threadIdx.x;
    int lane = tid & 63, wave = tid >> 6;
    const float* xb = x + (size_t)b * 3072;

    // nibble -> 4 bytes of +-1 i8 LUT (used by the phase-1 expansion)
    if (tid < 16) {
        unsigned int v = 0;
#pragma unroll
        for (int j = 0; j < 4; ++j) v |= (((tid >> j) & 1) ? 0x01u : 0xFFu) << (8 * j);
        lut[tid] = v;
    }

    // ================= phase 0: conv0 via f16 MFMA (pool-ordered im2col) =================
    {
        for (int i = tid; i < 3072; i += 256) {
            int c = i >> 10, rem = i & 1023;
            u.p0.xh[c * 1057 + (rem >> 5) * 33 + (rem & 31)] = (_Float16)xb[i];
        }
        const uint4* bs4 = (const uint4*)bsigG;
        const uint4* ba4 = (const uint4*)babsG;
        for (int i = tid; i < 512; i += 256) { u.p0.bfrag[i] = bs4[i]; u.p0.bfraga[i] = ba4[i]; }
        if (tid == 0) qcnt = 0;

        int k0 = (lane >> 4) * 8;
        int offj[8];
#pragma unroll
        for (int j = 0; j < 8; j++) {
            int k = k0 + j;
            int c = k / 9, r = (k % 9) / 3, q = k % 3;
            offj[j] = c * 1057 + r * 33 + q;
        }
        unsigned short* b1u16 = (unsigned short*)bs.bits1;
        __syncthreads();

        for (int mt = wave; mt < 57; mt += 4) {   // M = 225*4 = 900 -> 57 tiles
            int mg = mt * 16 + (lane & 15);
            int me = mg < 900 ? mg : 899;
            int p = me >> 2, win = me & 3;
            int py = p / 15, px = p - py * 15;
            int base = (py * 2 + (win >> 1)) * 33 + px * 2 + (win & 1);
            v8h a;
#pragma unroll
            for (int j = 0; j < 8; j++)
                a[j] = (k0 + j < 27) ? u.p0.xh[base + offj[j]] : (_Float16)0.f;
            HU ua; ua.h = a;                      // |A| for the error-bound MFMA
            ua.u.x &= 0x7FFF7FFFu; ua.u.y &= 0x7FFF7FFFu;
            ua.u.z &= 0x7FFF7FFFu; ua.u.w &= 0x7FFF7FFFu;
            int myp = mt * 4 + (lane >> 4);
#pragma unroll
            for (int nt = 0; nt < 8; nt++) {
                HU bsf; bsf.u = u.p0.bfrag[nt * 64 + lane];
                HU baf; baf.u = u.p0.bfraga[nt * 64 + lane];
                v4f s  = __builtin_amdgcn_mfma_f32_16x16x32_f16(a,    bsf.h, (v4f){0.f,0.f,0.f,0.f}, 0, 0, 0);
                v4f sa = __builtin_amdgcn_mfma_f32_16x16x32_f16(ua.h, baf.h, (v4f){0.f,0.f,0.f,0.f}, 0, 0, 0);
                // rigorous f16-rounding bounds; sign logic as wave-mask ballots
                float bd0 = fmaf(sa[0], 1.1e-3f, 1e-5f);
                float bd1 = fmaf(sa[1], 1.1e-3f, 1e-5f);
                float bd2 = fmaf(sa[2], 1.1e-3f, 1e-5f);
                float bd3 = fmaf(sa[3], 1.1e-3f, 1e-5f);
                unsigned long long mkpos =
                    __ballot(s[0] >= bd0) | __ballot(s[1] >= bd1) |
                    __ballot(s[2] >= bd2) | __ballot(s[3] >= bd3);
                unsigned long long mkunc =
                    (__ballot(fabsf(s[0]) < bd0) | __ballot(fabsf(s[1]) < bd1) |
                     __ballot(fabsf(s[2]) < bd2) | __ballot(fabsf(s[3]) < bd3)) & ~mkpos;
                if ((lane & 15) == 0 && myp < 225)
                    b1u16[myp * 8 + nt] = (unsigned short)(mkpos >> (lane & 48));
                if (__builtin_expect(mkunc != 0ull, 0)) {
                    if (((mkunc >> lane) & 1ull) && myp < 225) {
                        unsigned int qi = atomicAdd(&qcnt, 1u);
                        if (qi < 256) queue[qi] = (unsigned)myp | ((unsigned)(nt * 16 + (lane & 15)) << 8);
                    }
                }
            }
        }
        __syncthreads();
        // ---- drain queue: exact f64 signs from GLOBAL f32 x (rare; all 4 windows) ----
        unsigned int nq = qcnt < 256u ? qcnt : 256u;
        for (unsigned int i = tid; i < nq; i += 256) {
            unsigned int e = queue[i];
            int p = e & 255; int oc = (e >> 8) & 255;
            int py = p / 15, px = p - py * 15;
            bool pos = false;
#pragma unroll
            for (int win = 0; win < 4; win++) {
                int base = (py * 2 + (win >> 1)) * 32 + px * 2 + (win & 1);
                double sd = 0.0;
#pragma unroll
                for (int k = 0; k < 27; k++) {
                    int c = k / 9, r = (k % 9) / 3, q = k % 3;
                    sd += (double)xb[base + c * 1024 + r * 32 + q] * (double)w0[oc * 27 + k];
                }
                pos |= (sd >= 0.0);
            }
            if (pos) atomicOr(&bs.bits1[p * 2 + (oc >> 6)], 1ull << (oc & 63));
        }
    }
    __syncthreads();

    // ========== phase 1a: expand bits1 -> +-1 i8 [225][144B] (overlays phase-0 LDS) ==========
    if (tid < 225) {
        ulonglong2 bw = ((const ulonglong2*)bs.bits1)[tid];
        unsigned char* dst = u.expb + tid * 144;
#pragma unroll
        for (int c2 = 0; c2 < 2; ++c2) {
            unsigned long long v = c2 ? bw.y : bw.x;
#pragma unroll
            for (int c = 0; c < 4; ++c) {
                uint4 d;
                d.x = lut[(v >> (c * 16 +  0)) & 15];
                d.y = lut[(v >> (c * 16 +  4)) & 15];
                d.z = lut[(v >> (c * 16 +  8)) & 15];
                d.w = lut[(v >> (c * 16 + 12)) & 15];
                *(uint4*)(dst + (c2 * 4 + c) * 16) = d;
            }
        }
    }
    __syncthreads();

    // ========== phase 1b: binconv1 via i8 MFMA, each wave owns 2 nt (16 oc each) ==========
    {
        int posb144_[9];
#pragma unroll
        for (int mt = 0; mt < 9; ++mt) {
            int w = mt * 16 + (lane & 15);         // window row 0..143
            int wy = w / 12, wx = w - wy * 12;
            posb144_[mt] = (wy * 15 + wx) * 144;
        }
        int g16 = (lane >> 4) * 16;                // k-byte base within 64-slice

        for (int pass = 0; pass < 2; ++pass) {
            int nt = wave * 2 + pass;
            v4i acc[9];
#pragma unroll
            for (int mt = 0; mt < 9; ++mt) acc[mt] = (v4i){0, 0, 0, 0};
#pragma unroll 2
            for (int tk = 0; tk < 18; ++tk) {      // tap*2+kk
                int tap = tk >> 1, kk = tk & 1;
                int tapoff = tap + (tap / 3) * 12; // ky*15+kx
                int utk = tapoff * 144 + kk * 64 + g16;
                uint4 bfr = bw1f[(tk * 8 + nt) * 64 + lane];
                v4i bf; bf.x = (int)bfr.x; bf.y = (int)bfr.y; bf.z = (int)bfr.z; bf.w = (int)bfr.w;
#pragma unroll
                for (int mt = 0; mt < 9; ++mt) {
                    v4i af = *(const v4i*)(u.expb + (posb144_[mt] + utk));
                    acc[mt] = __builtin_amdgcn_mfma_i32_16x16x64_i8(af, bf, acc[mt], 0, 0, 0);
                }
            }
            // signs -> sgn1[w][nt] as u16 oc-slices (same ballot idiom as phase 0)
#pragma unroll
            for (int mt = 0; mt < 9; ++mt) {
#pragma unroll
                for (int r = 0; r < 4; ++r) {
                    unsigned long long mm = __ballot(acc[mt][r] >= 0);
                    if ((lane & 15) == 0)
                        bs.sgn1[(mt * 16 + (lane >> 4) * 4 + r) * 8 + nt] =
                            (unsigned short)(mm >> lane);
                }
            }
        }
    }
    __syncthreads();

    int wave2 = tid >> 6, half = wave2 & 1, pair = wave2 >> 1;
    int oc = half * 64 + lane;

    // ========== phase 1c: maxpool 2x2 s2 over window signs -> bits2 ==========
    {
        int idx = oc >> 4, sh = oc & 15;
        for (int p = pair; p < 36; p += 2) {
            int py = p / 6, px = p % 6;
            int w0i = (2 * py) * 12 + 2 * px;
            unsigned v = (unsigned)bs.sgn1[w0i * 8 + idx]        | (unsigned)bs.sgn1[(w0i + 1) * 8 + idx]
                       | (unsigned)bs.sgn1[(w0i + 12) * 8 + idx] | (unsigned)bs.sgn1[(w0i + 13) * 8 + idx];
            unsigned long long m = __ballot(((v >> sh) & 1u) != 0u);
            if (lane == 0) bits2[p * 2 + half] = m;
        }
    }
    __syncthreads();

    // ================= phase 2: binconv2 (6->4) + maxpool(2,s1) (->3) =================
    {
        unsigned long long wr[18];
#pragma unroll
        for (int j = 0; j < 18; j++) wr[j] = wb2[oc * 18 + j];
        const ulonglong2* b2v = (const ulonglong2*)bits2;
        for (int p = pair; p < 9; p += 2) {
            int py = p / 3, px = p % 3;
            int P4[4];
#pragma unroll
            for (int dy = 0; dy < 2; dy++)
#pragma unroll
                for (int dx = 0; dx < 2; dx++) {
                    int P = 0;
#pragma unroll
                    for (int ky = 0; ky < 3; ky++)
#pragma unroll
                        for (int kx = 0; kx < 3; kx++) {
                            ulonglong2 q = b2v[(py + dy + ky) * 6 + (px + dx + kx)];
                            P += __popcll(q.x ^ wr[(ky * 3 + kx) * 2]);
                            P += __popcll(q.y ^ wr[(ky * 3 + kx) * 2 + 1]);
                        }
                    P4[dy * 2 + dx] = P;
                }
            unsigned long long m = __ballot(P4[0] <= 576) | __ballot(P4[1] <= 576) |
                                   __ballot(P4[2] <= 576) | __ballot(P4[3] <= 576);
            if (lane == 0) bits3[p * 2 + half] = m;
        }
    }
    __syncthreads();

    // ================= phase 3: binconv3 + binconv4 + relu + w5 + softmax =================
    if (tid < 128) {
        int P = 0;
#pragma unroll
        for (int k = 0; k < 9; k++) {
            P += __popcll(bits3[k * 2] ^ wb3[tid * 18 + k * 2]);
            P += __popcll(bits3[k * 2 + 1] ^ wb3[tid * 18 + k * 2 + 1]);
        }
        unsigned long long m = __ballot(P <= 576);
        if ((tid & 63) == 0) bits4[tid >> 6] = m;
    }
    __syncthreads();
    if (tid < 128) {
        unsigned long long i0 = bits4[0], i1 = bits4[1];
        int v = 128 - 2 * (int)(__popcll(i0 ^ wb4[tid * 2]) + __popcll(i1 ^ wb4[tid * 2 + 1]));
        r_s[tid] = v > 0 ? (float)v : 0.f;   // relu
    }
    __syncthreads();
    if (tid < NUM_CLS) {
        float l = 0.f;
#pragma unroll 8
        for (int k = 0; k < 128; k++) l = fmaf(w5[tid * 128 + k], r_s[k], l);
        l_s[tid] = l;
    }
    __syncthreads();
    if (tid < NUM_CLS) {
        float mx = -1e30f;
        for (int k = 0; k < NUM_CLS; k++) mx = fmaxf(mx, l_s[k]);
        e_s[tid] = expf(l_s[tid] - mx);
    }
    __syncthreads();
    if (tid < NUM_CLS) {
        float sum = 0.f;
        for (int k = 0; k < NUM_CLS; k++) sum += e_s[k];
        out[(size_t)b * NUM_CLS + tid] = e_s[tid] / sum;
    }
}

extern "C" void kernel_launch(void* const* d_in, const int* in_sizes, int n_in,
                              void* d_out, int out_size, void* d_ws, size_t ws_size,
                              hipStream_t stream) {
    const float* x  = (const float*)d_in[0];
    const float* w0 = (const float*)d_in[1];
    const float* w1 = (const float*)d_in[2];
    const float* w2 = (const float*)d_in[3];
    const float* w3 = (const float*)d_in[4];
    const float* w4 = (const float*)d_in[5];
    const float* w5 = (const float*)d_in[6];
    float* out = (float*)d_out;

    int B = in_sizes[0] / 3072;   // 1024

    size_t off = 0;
    auto carve = [&](size_t bytes) {
        void* p = (char*)d_ws + off;
        off += (bytes + 255) & ~(size_t)255;
        return p;
    };
    unsigned long long* wb2 = (unsigned long long*)carve(1152 * 2 * 8);
    unsigned long long* wb3 = (unsigned long long*)carve(1152 * 2 * 8);
    unsigned long long* wb4 = (unsigned long long*)carve(128 * 2 * 8);
    _Float16* bsig = (_Float16*)carve(8 * 64 * 8 * 2);   // conv0 MFMA B-frags (signed)
    _Float16* babs = (_Float16*)carve(8 * 64 * 8 * 2);   // conv0 MFMA B-frags (abs)
    uint4* bw1f = (uint4*)carve(18 * 8 * 64 * 16);       // w1 i8 frags, 147456 B
    (void)ws_size; (void)n_in; (void)out_size;

    prep_all<<<326, 256, 0, stream>>>(w0, w1, w2, w3, w4, wb2, wb3, wb4, bsig, babs, bw1f);
    fused_net<<<B, 256, 0, stream>>>(x, w0, bsig, babs, bw1f, wb2, wb3, wb4, w5, out);
}

// Round 5
// 142.887 us; speedup vs baseline: 2.0723x; 1.0515x over previous
//
#include <hip/hip_runtime.h>
#include <cmath>

#define NUM_CLS 58

typedef _Float16 v8h __attribute__((ext_vector_type(8)));
typedef float v4f __attribute__((ext_vector_type(4)));
typedef int v4i __attribute__((ext_vector_type(4)));
union HU { v8h h; uint4 u; };

// ---------------- prep v4 ----------------
// blocks 0..255   : per-oc binarize of w2/w3 (layer=id>>7, oc=id&127)
// blocks 256..287 : w4 binarize (1 oc per wave)
// blocks 288..289 : w0 MFMA B-fragments, signed + abs (4 nt per block)
// blocks 290..325 : w1 -> +-1 i8 MFMA B-fragments [tk=18][nt=8][lane=64][16B]
__global__ __launch_bounds__(256) void prep_all(
    const float* __restrict__ w0, const float* __restrict__ w1,
    const float* __restrict__ w2, const float* __restrict__ w3,
    const float* __restrict__ w4,
    unsigned long long* __restrict__ wb2,
    unsigned long long* __restrict__ wb3, unsigned long long* __restrict__ wb4,
    _Float16* __restrict__ bsig, _Float16* __restrict__ babs,
    uint4* __restrict__ bw1f) {
    int id = blockIdx.x, tid = threadIdx.x;
    int lane = tid & 63, wv = tid >> 6;
    if (id < 256) {
        int layer = id >> 7, oc = id & 127;
        const float* w = layer == 0 ? w2 : w3;
        unsigned long long* o = layer == 0 ? wb2 : wb3;
        __shared__ float s[1152];
        const float* base = w + (size_t)oc * 1152;
        for (int i = tid; i < 1152; i += 256) s[i] = base[i];   // coalesced
        __syncthreads();
        for (int k = wv; k < 9; k += 4) {    // stride-9 LDS reads: 2-way banks, free
            unsigned long long b0 = __ballot(s[lane * 9 + k] >= 0.f);
            unsigned long long b1 = __ballot(s[(lane + 64) * 9 + k] >= 0.f);
            if (lane == 0) { o[(oc * 9 + k) * 2] = b0; o[(oc * 9 + k) * 2 + 1] = b1; }
        }
    } else if (id < 288) {
        int oc = (id - 256) * 4 + wv;        // 128 oc over 32 blocks x 4 waves
        unsigned long long b0 = __ballot(w4[oc * 128 + lane] >= 0.f);
        unsigned long long b1 = __ballot(w4[oc * 128 + lane + 64] >= 0.f);
        if (lane == 0) { wb4[oc * 2] = b0; wb4[oc * 2 + 1] = b1; }
    } else if (id < 290) {
        int nt = (id - 288) * 4 + wv;        // 8 nt over 2 blocks x 4 waves
        int n = nt * 16 + (lane & 15);
        int k0 = (lane >> 4) * 8;
#pragma unroll
        for (int j = 0; j < 8; j++) {
            int k = k0 + j;
            float v = (k < 27) ? w0[n * 27 + k] : 0.f;
            bsig[(nt * 64 + lane) * 8 + j] = (_Float16)v;
            babs[(nt * 64 + lane) * 8 + j] = (_Float16)fabsf(v);
        }
    } else {
        // w1 i8 fragments: frag fi=(tk,nt,ln); byte j = sign(w1[oc=nt*16+(ln&15)]
        //   [ic=kk*64+(ln>>4)*16+j][tap]) as +1/-1 i8. w1 idx = oc*1152 + ic*9 + tap.
        int fi = (id - 290) * 256 + tid;     // 0..9215
        int tk = fi >> 9;                    // 0..17 (tap*2+kk)
        int rem = fi & 511;
        int nt = rem >> 6, ln = rem & 63;
        int oc = nt * 16 + (ln & 15);
        int tap = tk >> 1, kk = tk & 1;
        int icb = kk * 64 + (ln >> 4) * 16;
        const float* wp = w1 + (size_t)oc * 1152 + tap;
        unsigned int dd[4];
#pragma unroll
        for (int q = 0; q < 4; ++q) {
            unsigned int v = 0;
#pragma unroll
            for (int j = 0; j < 4; ++j)
                v |= (wp[(icb + q * 4 + j) * 9] >= 0.f ? 0x01u : 0xFFu) << (8 * j);
            dd[q] = v;
        }
        uint4 d; d.x = dd[0]; d.y = dd[1]; d.z = dd[2]; d.w = dd[3];
        bw1f[fi] = d;
    }
}

// LDS overlays: phase-0 staging set and the phase-1 i8 expansion share one union
// (xh/bfrag/bfraga dead after the post-drain barrier). sgn1 overlays bits1.
// r5: expb is [225 rows][128 B] LINEAR rows + XOR-chunk swizzle
// (chunk ^= row&7, i.e. byte ^= ((row&7)<<4)) — the G4/T2 measured pattern for
// "lanes read different rows at same col": r4's stride-144 pad left ~8 extra
// conflict cycles per ds_read_b128 (SQ_LDS_BANK_CONFLICT 11.26M, ~10k cyc/blk).
// Also saves 3.6 KB LDS vs the 144-stride pad.
union UEXP {
    struct {
        _Float16 xh[3172];                 // image f16; row stride 33, chan stride 1057
        alignas(16) uint4 bfrag[512];      // conv0 B sign-fragments (8 KB)
        uint4 bfraga[512];                 // conv0 |B| fragments (8 KB)
    } p0;
    unsigned char expb[225 * 128];         // +-1 i8 input, [pos][128B], XOR-swizzled chunks
};
union BS {
    alignas(16) unsigned long long bits1[450];  // [15*15][2]
    unsigned short sgn1[144 * 8];               // binconv1 window signs [w][nt]
};

// ---- one block per batch element, 4 waves (REGISTER WALL, measured r1/r2) ----
// Occupancy ladder CLOSED: min-waves>4 caps unified regs at 512/w, compiler
// splits arch/acc ~50/50, this kernel needs ~64 arch -> spills (131-449MB).
// r4: binconv1 = EXACT i8 MFMA (C = 1152-2P, sign identical). 86us, VALU 44%,
// Mfma 17% — stall-bound on phase-1b LDS bank conflicts -> r5 XOR swizzle.
__global__ __launch_bounds__(256, 4) void fused_net(
    const float* __restrict__ x, const float* __restrict__ w0,
    const _Float16* __restrict__ bsigG, const _Float16* __restrict__ babsG,
    const uint4* __restrict__ bw1f, const unsigned long long* __restrict__ wb2,
    const unsigned long long* __restrict__ wb3, const unsigned long long* __restrict__ wb4,
    const float* __restrict__ w5, float* __restrict__ out) {
    __shared__ UEXP u;
    __shared__ BS bs;
    __shared__ unsigned int lut[16];
    __shared__ alignas(16) unsigned long long bits2[72];
    __shared__ unsigned long long bits3[18];
    __shared__ unsigned long long bits4[2];
    __shared__ float r_s[128];
    __shared__ float l_s[NUM_CLS];
    __shared__ float e_s[NUM_CLS];
    __shared__ unsigned int qcnt;
    __shared__ unsigned int queue[256];

    int b = blockIdx.x;
    int tid = threadIdx.x;
    int lane = tid & 63, wave = tid >> 6;
    const float* xb = x + (size_t)b * 3072;

    // nibble -> 4 bytes of +-1 i8 LUT (used by the phase-1 expansion)
    if (tid < 16) {
        unsigned int v = 0;
#pragma unroll
        for (int j = 0; j < 4; ++j) v |= (((tid >> j) & 1) ? 0x01u : 0xFFu) << (8 * j);
        lut[tid] = v;
    }

    // ================= phase 0: conv0 via f16 MFMA (pool-ordered im2col) =================
    {
        for (int i = tid; i < 3072; i += 256) {
            int c = i >> 10, rem = i & 1023;
            u.p0.xh[c * 1057 + (rem >> 5) * 33 + (rem & 31)] = (_Float16)xb[i];
        }
        const uint4* bs4 = (const uint4*)bsigG;
        const uint4* ba4 = (const uint4*)babsG;
        for (int i = tid; i < 512; i += 256) { u.p0.bfrag[i] = bs4[i]; u.p0.bfraga[i] = ba4[i]; }
        if (tid == 0) qcnt = 0;

        int k0 = (lane >> 4) * 8;
        int offj[8];
#pragma unroll
        for (int j = 0; j < 8; j++) {
            int k = k0 + j;
            int c = k / 9, r = (k % 9) / 3, q = k % 3;
            offj[j] = c * 1057 + r * 33 + q;
        }
        unsigned short* b1u16 = (unsigned short*)bs.bits1;
        __syncthreads();

        for (int mt = wave; mt < 57; mt += 4) {   // M = 225*4 = 900 -> 57 tiles
            int mg = mt * 16 + (lane & 15);
            int me = mg < 900 ? mg : 899;
            int p = me >> 2, win = me & 3;
            int py = p / 15, px = p - py * 15;
            int base = (py * 2 + (win >> 1)) * 33 + px * 2 + (win & 1);
            v8h a;
#pragma unroll
            for (int j = 0; j < 8; j++)
                a[j] = (k0 + j < 27) ? u.p0.xh[base + offj[j]] : (_Float16)0.f;
            HU ua; ua.h = a;                      // |A| for the error-bound MFMA
            ua.u.x &= 0x7FFF7FFFu; ua.u.y &= 0x7FFF7FFFu;
            ua.u.z &= 0x7FFF7FFFu; ua.u.w &= 0x7FFF7FFFu;
            int myp = mt * 4 + (lane >> 4);
#pragma unroll
            for (int nt = 0; nt < 8; nt++) {
                HU bsf; bsf.u = u.p0.bfrag[nt * 64 + lane];
                HU baf; baf.u = u.p0.bfraga[nt * 64 + lane];
                v4f s  = __builtin_amdgcn_mfma_f32_16x16x32_f16(a,    bsf.h, (v4f){0.f,0.f,0.f,0.f}, 0, 0, 0);
                v4f sa = __builtin_amdgcn_mfma_f32_16x16x32_f16(ua.h, baf.h, (v4f){0.f,0.f,0.f,0.f}, 0, 0, 0);
                // rigorous f16-rounding bounds; sign logic as wave-mask ballots
                float bd0 = fmaf(sa[0], 1.1e-3f, 1e-5f);
                float bd1 = fmaf(sa[1], 1.1e-3f, 1e-5f);
                float bd2 = fmaf(sa[2], 1.1e-3f, 1e-5f);
                float bd3 = fmaf(sa[3], 1.1e-3f, 1e-5f);
                unsigned long long mkpos =
                    __ballot(s[0] >= bd0) | __ballot(s[1] >= bd1) |
                    __ballot(s[2] >= bd2) | __ballot(s[3] >= bd3);
                unsigned long long mkunc =
                    (__ballot(fabsf(s[0]) < bd0) | __ballot(fabsf(s[1]) < bd1) |
                     __ballot(fabsf(s[2]) < bd2) | __ballot(fabsf(s[3]) < bd3)) & ~mkpos;
                if ((lane & 15) == 0 && myp < 225)
                    b1u16[myp * 8 + nt] = (unsigned short)(mkpos >> (lane & 48));
                if (__builtin_expect(mkunc != 0ull, 0)) {
                    if (((mkunc >> lane) & 1ull) && myp < 225) {
                        unsigned int qi = atomicAdd(&qcnt, 1u);
                        if (qi < 256) queue[qi] = (unsigned)myp | ((unsigned)(nt * 16 + (lane & 15)) << 8);
                    }
                }
            }
        }
        __syncthreads();
        // ---- drain queue: exact f64 signs from GLOBAL f32 x (rare; all 4 windows) ----
        unsigned int nq = qcnt < 256u ? qcnt : 256u;
        for (unsigned int i = tid; i < nq; i += 256) {
            unsigned int e = queue[i];
            int p = e & 255; int oc = (e >> 8) & 255;
            int py = p / 15, px = p - py * 15;
            bool pos = false;
#pragma unroll
            for (int win = 0; win < 4; win++) {
                int base = (py * 2 + (win >> 1)) * 32 + px * 2 + (win & 1);
                double sd = 0.0;
#pragma unroll
                for (int k = 0; k < 27; k++) {
                    int c = k / 9, r = (k % 9) / 3, q = k % 3;
                    sd += (double)xb[base + c * 1024 + r * 32 + q] * (double)w0[oc * 27 + k];
                }
                pos |= (sd >= 0.0);
            }
            if (pos) atomicOr(&bs.bits1[p * 2 + (oc >> 6)], 1ull << (oc & 63));
        }
    }
    __syncthreads();

    // ========== phase 1a: expand bits1 -> +-1 i8 [225][128B], XOR-swizzled chunks ==========
    if (tid < 225) {
        ulonglong2 bw = ((const ulonglong2*)bs.bits1)[tid];
        unsigned char* dst = u.expb + tid * 128;
        int sw = (tid & 7) << 4;                   // row-XOR swizzle
#pragma unroll
        for (int c2 = 0; c2 < 2; ++c2) {
            unsigned long long v = c2 ? bw.y : bw.x;
#pragma unroll
            for (int c = 0; c < 4; ++c) {
                uint4 d;
                d.x = lut[(v >> (c * 16 +  0)) & 15];
                d.y = lut[(v >> (c * 16 +  4)) & 15];
                d.z = lut[(v >> (c * 16 +  8)) & 15];
                d.w = lut[(v >> (c * 16 + 12)) & 15];
                *(uint4*)(dst + (((c2 * 4 + c) * 16) ^ sw)) = d;
            }
        }
    }
    __syncthreads();

    // ========== phase 1b: binconv1 via i8 MFMA, each wave owns 2 nt (16 oc each) ==========
    {
        int pg_[9];                                // pos*128 + (lane>>4)*16
#pragma unroll
        for (int mt = 0; mt < 9; ++mt) {
            int w = mt * 16 + (lane & 15);         // window row 0..143
            int wy = w / 12, wx = w - wy * 12;
            pg_[mt] = (wy * 15 + wx) * 128 + ((lane >> 4) << 4);
        }

        for (int pass = 0; pass < 2; ++pass) {
            int nt = wave * 2 + pass;
            v4i acc[9];
#pragma unroll
            for (int mt = 0; mt < 9; ++mt) acc[mt] = (v4i){0, 0, 0, 0};
#pragma unroll 2
            for (int tk = 0; tk < 18; ++tk) {      // tap*2+kk
                int tap = tk >> 1, kk = tk & 1;
                int tapoff = tap + (tap / 3) * 12; // ky*15+kx
                int tks = tapoff * 128 + kk * 64;
                uint4 bfr = bw1f[(tk * 8 + nt) * 64 + lane];
                v4i bf; bf.x = (int)bfr.x; bf.y = (int)bfr.y; bf.z = (int)bfr.z; bf.w = (int)bfr.w;
#pragma unroll
                for (int mt = 0; mt < 9; ++mt) {
                    // row = pos+tapoff; chunk<128 never carries into bit7, so
                    // full ^ ((full>>3)&0x70) == row*128 + (chunk16 ^ ((row&7)<<4))
                    int full = pg_[mt] + tks;
                    int addr = full ^ ((full >> 3) & 0x70);
                    v4i af = *(const v4i*)(u.expb + addr);
                    acc[mt] = __builtin_amdgcn_mfma_i32_16x16x64_i8(af, bf, acc[mt], 0, 0, 0);
                }
            }
            // signs -> sgn1[w][nt] as u16 oc-slices (same ballot idiom as phase 0)
#pragma unroll
            for (int mt = 0; mt < 9; ++mt) {
#pragma unroll
                for (int r = 0; r < 4; ++r) {
                    unsigned long long mm = __ballot(acc[mt][r] >= 0);
                    if ((lane & 15) == 0)
                        bs.sgn1[(mt * 16 + (lane >> 4) * 4 + r) * 8 + nt] =
                            (unsigned short)(mm >> lane);
                }
            }
        }
    }
    __syncthreads();

    int wave2 = tid >> 6, half = wave2 & 1, pair = wave2 >> 1;
    int oc = half * 64 + lane;

    // ========== phase 1c: maxpool 2x2 s2 over window signs -> bits2 ==========
    {
        int idx = oc >> 4, sh = oc & 15;
        for (int p = pair; p < 36; p += 2) {
            int py = p / 6, px = p % 6;
            int w0i = (2 * py) * 12 + 2 * px;
            unsigned v = (unsigned)bs.sgn1[w0i * 8 + idx]        | (unsigned)bs.sgn1[(w0i + 1) * 8 + idx]
                       | (unsigned)bs.sgn1[(w0i + 12) * 8 + idx] | (unsigned)bs.sgn1[(w0i + 13) * 8 + idx];
            unsigned long long m = __ballot(((v >> sh) & 1u) != 0u);
            if (lane == 0) bits2[p * 2 + half] = m;
        }
    }
    __syncthreads();

    // ================= phase 2: binconv2 (6->4) + maxpool(2,s1) (->3) =================
    {
        unsigned long long wr[18];
#pragma unroll
        for (int j = 0; j < 18; j++) wr[j] = wb2[oc * 18 + j];
        const ulonglong2* b2v = (const ulonglong2*)bits2;
        for (int p = pair; p < 9; p += 2) {
            int py = p / 3, px = p % 3;
            int P4[4];
#pragma unroll
            for (int dy = 0; dy < 2; dy++)
#pragma unroll
                for (int dx = 0; dx < 2; dx++) {
                    int P = 0;
#pragma unroll
                    for (int ky = 0; ky < 3; ky++)
#pragma unroll
                        for (int kx = 0; kx < 3; kx++) {
                            ulonglong2 q = b2v[(py + dy + ky) * 6 + (px + dx + kx)];
                            P += __popcll(q.x ^ wr[(ky * 3 + kx) * 2]);
                            P += __popcll(q.y ^ wr[(ky * 3 + kx) * 2 + 1]);
                        }
                    P4[dy * 2 + dx] = P;
                }
            unsigned long long m = __ballot(P4[0] <= 576) | __ballot(P4[1] <= 576) |
                                   __ballot(P4[2] <= 576) | __ballot(P4[3] <= 576);
            if (lane == 0) bits3[p * 2 + half] = m;
        }
    }
    __syncthreads();

    // ================= phase 3: binconv3 + binconv4 + relu + w5 + softmax =================
    if (tid < 128) {
        int P = 0;
#pragma unroll
        for (int k = 0; k < 9; k++) {
            P += __popcll(bits3[k * 2] ^ wb3[tid * 18 + k * 2]);
            P += __popcll(bits3[k * 2 + 1] ^ wb3[tid * 18 + k * 2 + 1]);
        }
        unsigned long long m = __ballot(P <= 576);
        if ((tid & 63) == 0) bits4[tid >> 6] = m;
    }
    __syncthreads();
    if (tid < 128) {
        unsigned long long i0 = bits4[0], i1 = bits4[1];
        int v = 128 - 2 * (int)(__popcll(i0 ^ wb4[tid * 2]) + __popcll(i1 ^ wb4[tid * 2 + 1]));
        r_s[tid] = v > 0 ? (float)v : 0.f;   // relu
    }
    __syncthreads();
    if (tid < NUM_CLS) {
        float l = 0.f;
#pragma unroll 8
        for (int k = 0; k < 128; k++) l = fmaf(w5[tid * 128 + k], r_s[k], l);
        l_s[tid] = l;
    }
    __syncthreads();
    if (tid < NUM_CLS) {
        float mx = -1e30f;
        for (int k = 0; k < NUM_CLS; k++) mx = fmaxf(mx, l_s[k]);
        e_s[tid] = expf(l_s[tid] - mx);
    }
    __syncthreads();
    if (tid < NUM_CLS) {
        float sum = 0.f;
        for (int k = 0; k < NUM_CLS; k++) sum += e_s[k];
        out[(size_t)b * NUM_CLS + tid] = e_s[tid] / sum;
    }
}

extern "C" void kernel_launch(void* const* d_in, const int* in_sizes, int n_in,
                              void* d_out, int out_size, void* d_ws, size_t ws_size,
                              hipStream_t stream) {
    const float* x  = (const float*)d_in[0];
    const float* w0 = (const float*)d_in[1];
    const float* w1 = (const float*)d_in[2];
    const float* w2 = (const float*)d_in[3];
    const float* w3 = (const float*)d_in[4];
    const float* w4 = (const float*)d_in[5];
    const float* w5 = (const float*)d_in[6];
    float* out = (float*)d_out;

    int B = in_sizes[0] / 3072;   // 1024

    size_t off = 0;
    auto carve = [&](size_t bytes) {
        void* p = (char*)d_ws + off;
        off += (bytes + 255) & ~(size_t)255;
        return p;
    };
    unsigned long long* wb2 = (unsigned long long*)carve(1152 * 2 * 8);
    unsigned long long* wb3 = (unsigned long long*)carve(1152 * 2 * 8);
    unsigned long long* wb4 = (unsigned long long*)carve(128 * 2 * 8);
    _Float16* bsig = (_Float16*)carve(8 * 64 * 8 * 2);   // conv0 MFMA B-frags (signed)
    _Float16* babs = (_Float16*)carve(8 * 64 * 8 * 2);   // conv0 MFMA B-frags (abs)
    uint4* bw1f = (uint4*)carve(18 * 8 * 64 * 16);       // w1 i8 frags, 147456 B
    (void)ws_size; (void)n_in; (void)out_size;

    prep_all<<<326, 256, 0, stream>>>(w0, w1, w2, w3, w4, wb2, wb3, wb4, bsig, babs, bw1f);
    fused_net<<<B, 256, 0, stream>>>(x, w0, bsig, babs, bw1f, wb2, wb3, wb4, w5, out);
}

// Round 6
// 139.265 us; speedup vs baseline: 2.1262x; 1.0260x over previous
//
#include <hip/hip_runtime.h>
#include <cmath>

#define NUM_CLS 58

typedef _Float16 v8h __attribute__((ext_vector_type(8)));
typedef float v4f __attribute__((ext_vector_type(4)));
typedef int v4i __attribute__((ext_vector_type(4)));
union HU { v8h h; uint4 u; };
template<int N> struct IC { static constexpr int value = N; };

// ---------------- prep v4 ----------------
// blocks 0..255   : per-oc binarize of w2/w3 (layer=id>>7, oc=id&127)
// blocks 256..287 : w4 binarize (1 oc per wave)
// blocks 288..289 : w0 MFMA B-fragments, signed + abs (4 nt per block)
// blocks 290..325 : w1 -> +-1 i8 MFMA B-fragments [tk=18][nt=8][lane=64][16B]
__global__ __launch_bounds__(256) void prep_all(
    const float* __restrict__ w0, const float* __restrict__ w1,
    const float* __restrict__ w2, const float* __restrict__ w3,
    const float* __restrict__ w4,
    unsigned long long* __restrict__ wb2,
    unsigned long long* __restrict__ wb3, unsigned long long* __restrict__ wb4,
    _Float16* __restrict__ bsig, _Float16* __restrict__ babs,
    uint4* __restrict__ bw1f) {
    int id = blockIdx.x, tid = threadIdx.x;
    int lane = tid & 63, wv = tid >> 6;
    if (id < 256) {
        int layer = id >> 7, oc = id & 127;
        const float* w = layer == 0 ? w2 : w3;
        unsigned long long* o = layer == 0 ? wb2 : wb3;
        __shared__ float s[1152];
        const float* base = w + (size_t)oc * 1152;
        for (int i = tid; i < 1152; i += 256) s[i] = base[i];   // coalesced
        __syncthreads();
        for (int k = wv; k < 9; k += 4) {    // stride-9 LDS reads: 2-way banks, free
            unsigned long long b0 = __ballot(s[lane * 9 + k] >= 0.f);
            unsigned long long b1 = __ballot(s[(lane + 64) * 9 + k] >= 0.f);
            if (lane == 0) { o[(oc * 9 + k) * 2] = b0; o[(oc * 9 + k) * 2 + 1] = b1; }
        }
    } else if (id < 288) {
        int oc = (id - 256) * 4 + wv;        // 128 oc over 32 blocks x 4 waves
        unsigned long long b0 = __ballot(w4[oc * 128 + lane] >= 0.f);
        unsigned long long b1 = __ballot(w4[oc * 128 + lane + 64] >= 0.f);
        if (lane == 0) { wb4[oc * 2] = b0; wb4[oc * 2 + 1] = b1; }
    } else if (id < 290) {
        int nt = (id - 288) * 4 + wv;        // 8 nt over 2 blocks x 4 waves
        int n = nt * 16 + (lane & 15);
        int k0 = (lane >> 4) * 8;
#pragma unroll
        for (int j = 0; j < 8; j++) {
            int k = k0 + j;
            float v = (k < 27) ? w0[n * 27 + k] : 0.f;
            bsig[(nt * 64 + lane) * 8 + j] = (_Float16)v;
            babs[(nt * 64 + lane) * 8 + j] = (_Float16)fabsf(v);
        }
    } else {
        // w1 i8 fragments: frag fi=(tk,nt,ln); byte j = sign(w1[oc=nt*16+(ln&15)]
        //   [ic=kk*64+(ln>>4)*16+j][tap]) as +1/-1 i8. w1 idx = oc*1152 + ic*9 + tap.
        int fi = (id - 290) * 256 + tid;     // 0..9215
        int tk = fi >> 9;                    // 0..17 (tap*2+kk)
        int rem = fi & 511;
        int nt = rem >> 6, ln = rem & 63;
        int oc = nt * 16 + (ln & 15);
        int tap = tk >> 1, kk = tk & 1;
        int icb = kk * 64 + (ln >> 4) * 16;
        const float* wp = w1 + (size_t)oc * 1152 + tap;
        unsigned int dd[4];
#pragma unroll
        for (int q = 0; q < 4; ++q) {
            unsigned int v = 0;
#pragma unroll
            for (int j = 0; j < 4; ++j)
                v |= (wp[(icb + q * 4 + j) * 9] >= 0.f ? 0x01u : 0xFFu) << (8 * j);
            dd[q] = v;
        }
        uint4 d; d.x = dd[0]; d.y = dd[1]; d.z = dd[2]; d.w = dd[3];
        bw1f[fi] = d;
    }
}

// LDS overlays as before. r6: bfraga LDS buffer REMOVED — |B| f16 frags derived
// in-register from sign frags (f16 abs = &0x7FFF; 4 v_and vs 1 ds_read_b128 on
// the contended per-CU LDS pipe, measured ~65% busy). Saves 8 KB LDS too.
union UEXP {
    struct {
        _Float16 xh[3172];                 // image f16; row stride 33, chan stride 1057
        alignas(16) uint4 bfrag[512];      // conv0 B sign-fragments (8 KB)
    } p0;
    unsigned char expb[225 * 128];         // +-1 i8 input, [pos][128B], XOR-swizzled chunks
};
union BS {
    alignas(16) unsigned long long bits1[450];  // [15*15][2]
    unsigned short sgn1[144 * 8];               // binconv1 window signs [w][nt]
};

// ---- one block per batch element, 4 waves (REGISTER WALL, measured r1/r2) ----
// r4: binconv1 = EXACT i8 MFMA. r5: XOR swizzle (conflicts 11.3M->5.95M, 79us).
// r6: LDS-pipe load reduction. Accounting: phase0 ~11.7k + phase1b ~18k LDS
// cycles/block x 4 blocks/CU ~= 65% of the CU's LDS pipe — most-loaded pipe.
// (1) |B| frags derived in-register (phase 0: -8 b128/mt-iter).
// (2) phase-1b nt-passes FUSED: each af read feeds 2 MFMAs (324->162 reads).
//     acc split into mt-groups of 5+4 (peak 40 acc regs on the AGPR side of
//     the unified file; arch side stays under the 64-VGPR wall). All acc/pg
//     indices compile-time (IC<> lambda params) to avoid scratch (rule #20).
__global__ __launch_bounds__(256, 4) void fused_net(
    const float* __restrict__ x, const float* __restrict__ w0,
    const _Float16* __restrict__ bsigG, const _Float16* __restrict__ babsG,
    const uint4* __restrict__ bw1f, const unsigned long long* __restrict__ wb2,
    const unsigned long long* __restrict__ wb3, const unsigned long long* __restrict__ wb4,
    const float* __restrict__ w5, float* __restrict__ out) {
    __shared__ UEXP u;
    __shared__ BS bs;
    __shared__ unsigned int lut[16];
    __shared__ alignas(16) unsigned long long bits2[72];
    __shared__ unsigned long long bits3[18];
    __shared__ unsigned long long bits4[2];
    __shared__ float r_s[128];
    __shared__ float l_s[NUM_CLS];
    __shared__ float e_s[NUM_CLS];
    __shared__ unsigned int qcnt;
    __shared__ unsigned int queue[256];

    int b = blockIdx.x;
    int tid = threadIdx.x;
    int lane = tid & 63, wave = tid >> 6;
    const float* xb = x + (size_t)b * 3072;
    (void)babsG;   // |B| now derived in-register from bsigG fragments

    // nibble -> 4 bytes of +-1 i8 LUT (used by the phase-1 expansion)
    if (tid < 16) {
        unsigned int v = 0;
#pragma unroll
        for (int j = 0; j < 4; ++j) v |= (((tid >> j) & 1) ? 0x01u : 0xFFu) << (8 * j);
        lut[tid] = v;
    }

    // ================= phase 0: conv0 via f16 MFMA (pool-ordered im2col) =================
    {
        for (int i = tid; i < 3072; i += 256) {
            int c = i >> 10, rem = i & 1023;
            u.p0.xh[c * 1057 + (rem >> 5) * 33 + (rem & 31)] = (_Float16)xb[i];
        }
        const uint4* bs4 = (const uint4*)bsigG;
        for (int i = tid; i < 512; i += 256) u.p0.bfrag[i] = bs4[i];
        if (tid == 0) qcnt = 0;

        int k0 = (lane >> 4) * 8;
        int offj[8];
#pragma unroll
        for (int j = 0; j < 8; j++) {
            int k = k0 + j;
            int c = k / 9, r = (k % 9) / 3, q = k % 3;
            offj[j] = c * 1057 + r * 33 + q;
        }
        unsigned short* b1u16 = (unsigned short*)bs.bits1;
        __syncthreads();

        for (int mt = wave; mt < 57; mt += 4) {   // M = 225*4 = 900 -> 57 tiles
            int mg = mt * 16 + (lane & 15);
            int me = mg < 900 ? mg : 899;
            int p = me >> 2, win = me & 3;
            int py = p / 15, px = p - py * 15;
            int base = (py * 2 + (win >> 1)) * 33 + px * 2 + (win & 1);
            v8h a;
#pragma unroll
            for (int j = 0; j < 8; j++)
                a[j] = (k0 + j < 27) ? u.p0.xh[base + offj[j]] : (_Float16)0.f;
            HU ua; ua.h = a;                      // |A| for the error-bound MFMA
            ua.u.x &= 0x7FFF7FFFu; ua.u.y &= 0x7FFF7FFFu;
            ua.u.z &= 0x7FFF7FFFu; ua.u.w &= 0x7FFF7FFFu;
            int myp = mt * 4 + (lane >> 4);
#pragma unroll
            for (int nt = 0; nt < 8; nt++) {
                HU bsf; bsf.u = u.p0.bfrag[nt * 64 + lane];
                HU baf;                           // |B| in-register: f16 abs = clear sign bits
                baf.u.x = bsf.u.x & 0x7FFF7FFFu; baf.u.y = bsf.u.y & 0x7FFF7FFFu;
                baf.u.z = bsf.u.z & 0x7FFF7FFFu; baf.u.w = bsf.u.w & 0x7FFF7FFFu;
                v4f s  = __builtin_amdgcn_mfma_f32_16x16x32_f16(a,    bsf.h, (v4f){0.f,0.f,0.f,0.f}, 0, 0, 0);
                v4f sa = __builtin_amdgcn_mfma_f32_16x16x32_f16(ua.h, baf.h, (v4f){0.f,0.f,0.f,0.f}, 0, 0, 0);
                // rigorous f16-rounding bounds; sign logic as wave-mask ballots
                float bd0 = fmaf(sa[0], 1.1e-3f, 1e-5f);
                float bd1 = fmaf(sa[1], 1.1e-3f, 1e-5f);
                float bd2 = fmaf(sa[2], 1.1e-3f, 1e-5f);
                float bd3 = fmaf(sa[3], 1.1e-3f, 1e-5f);
                unsigned long long mkpos =
                    __ballot(s[0] >= bd0) | __ballot(s[1] >= bd1) |
                    __ballot(s[2] >= bd2) | __ballot(s[3] >= bd3);
                unsigned long long mkunc =
                    (__ballot(fabsf(s[0]) < bd0) | __ballot(fabsf(s[1]) < bd1) |
                     __ballot(fabsf(s[2]) < bd2) | __ballot(fabsf(s[3]) < bd3)) & ~mkpos;
                if ((lane & 15) == 0 && myp < 225)
                    b1u16[myp * 8 + nt] = (unsigned short)(mkpos >> (lane & 48));
                if (__builtin_expect(mkunc != 0ull, 0)) {
                    if (((mkunc >> lane) & 1ull) && myp < 225) {
                        unsigned int qi = atomicAdd(&qcnt, 1u);
                        if (qi < 256) queue[qi] = (unsigned)myp | ((unsigned)(nt * 16 + (lane & 15)) << 8);
                    }
                }
            }
        }
        __syncthreads();
        // ---- drain queue: exact f64 signs from GLOBAL f32 x (rare; all 4 windows) ----
        unsigned int nq = qcnt < 256u ? qcnt : 256u;
        for (unsigned int i = tid; i < nq; i += 256) {
            unsigned int e = queue[i];
            int p = e & 255; int oc = (e >> 8) & 255;
            int py = p / 15, px = p - py * 15;
            bool pos = false;
#pragma unroll
            for (int win = 0; win < 4; win++) {
                int base = (py * 2 + (win >> 1)) * 32 + px * 2 + (win & 1);
                double sd = 0.0;
#pragma unroll
                for (int k = 0; k < 27; k++) {
                    int c = k / 9, r = (k % 9) / 3, q = k % 3;
                    sd += (double)xb[base + c * 1024 + r * 32 + q] * (double)w0[oc * 27 + k];
                }
                pos |= (sd >= 0.0);
            }
            if (pos) atomicOr(&bs.bits1[p * 2 + (oc >> 6)], 1ull << (oc & 63));
        }
    }
    __syncthreads();

    // ========== phase 1a: expand bits1 -> +-1 i8 [225][128B], XOR-swizzled chunks ==========
    if (tid < 225) {
        ulonglong2 bw = ((const ulonglong2*)bs.bits1)[tid];
        unsigned char* dst = u.expb + tid * 128;
        int sw = (tid & 7) << 4;                   // row-XOR swizzle
#pragma unroll
        for (int c2 = 0; c2 < 2; ++c2) {
            unsigned long long v = c2 ? bw.y : bw.x;
#pragma unroll
            for (int c = 0; c < 4; ++c) {
                uint4 d;
                d.x = lut[(v >> (c * 16 +  0)) & 15];
                d.y = lut[(v >> (c * 16 +  4)) & 15];
                d.z = lut[(v >> (c * 16 +  8)) & 15];
                d.w = lut[(v >> (c * 16 + 12)) & 15];
                *(uint4*)(dst + (((c2 * 4 + c) * 16) ^ sw)) = d;
            }
        }
    }
    __syncthreads();

    // ========== phase 1b: binconv1 via i8 MFMA, nt-passes FUSED (af read once) ==========
    {
        int pg_[9];                                // pos*128 + (lane>>4)*16
#pragma unroll
        for (int mt = 0; mt < 9; ++mt) {
            int w = mt * 16 + (lane & 15);         // window row 0..143
            int wy = w / 12, wx = w - wy * 12;
            pg_[mt] = (wy * 15 + wx) * 128 + ((lane >> 4) << 4);
        }
        int ntA = wave * 2, ntB = wave * 2 + 1;

        auto run_group = [&](auto MT0_C, auto MTN_C) {
            constexpr int MT0 = MT0_C.value;
            constexpr int MTN = MTN_C.value;
            v4i acc0[MTN], acc1[MTN];
#pragma unroll
            for (int m = 0; m < MTN; ++m) { acc0[m] = (v4i){0,0,0,0}; acc1[m] = (v4i){0,0,0,0}; }
#pragma unroll 2
            for (int tk = 0; tk < 18; ++tk) {      // tap*2+kk
                int tap = tk >> 1, kk = tk & 1;
                int tapoff = tap + (tap / 3) * 12; // ky*15+kx
                int tks = tapoff * 128 + kk * 64;
                uint4 br0 = bw1f[(tk * 8 + ntA) * 64 + lane];
                uint4 br1 = bw1f[(tk * 8 + ntB) * 64 + lane];
                v4i b0; b0.x = (int)br0.x; b0.y = (int)br0.y; b0.z = (int)br0.z; b0.w = (int)br0.w;
                v4i b1; b1.x = (int)br1.x; b1.y = (int)br1.y; b1.z = (int)br1.z; b1.w = (int)br1.w;
#pragma unroll
                for (int m = 0; m < MTN; ++m) {
                    // row = pos+tapoff; chunk<128 never carries into bit7, so
                    // full ^ ((full>>3)&0x70) == row*128 + (chunk16 ^ ((row&7)<<4))
                    int full = pg_[MT0 + m] + tks;
                    int addr = full ^ ((full >> 3) & 0x70);
                    v4i af = *(const v4i*)(u.expb + addr);
                    acc0[m] = __builtin_amdgcn_mfma_i32_16x16x64_i8(af, b0, acc0[m], 0, 0, 0);
                    acc1[m] = __builtin_amdgcn_mfma_i32_16x16x64_i8(af, b1, acc1[m], 0, 0, 0);
                }
            }
            // signs -> sgn1[w][nt] as u16 oc-slices (same ballot idiom as phase 0)
#pragma unroll
            for (int m = 0; m < MTN; ++m) {
                constexpr int MTB = 0;  (void)MTB;
                int mt = MT0 + m;
#pragma unroll
                for (int r = 0; r < 4; ++r) {
                    unsigned long long m0 = __ballot(acc0[m][r] >= 0);
                    unsigned long long m1 = __ballot(acc1[m][r] >= 0);
                    if ((lane & 15) == 0) {
                        bs.sgn1[(mt * 16 + (lane >> 4) * 4 + r) * 8 + ntA] = (unsigned short)(m0 >> lane);
                        bs.sgn1[(mt * 16 + (lane >> 4) * 4 + r) * 8 + ntB] = (unsigned short)(m1 >> lane);
                    }
                }
            }
        };
        run_group(IC<0>{}, IC<5>{});
        run_group(IC<5>{}, IC<4>{});
    }
    __syncthreads();

    int wave2 = tid >> 6, half = wave2 & 1, pair = wave2 >> 1;
    int oc = half * 64 + lane;

    // ========== phase 1c: maxpool 2x2 s2 over window signs -> bits2 ==========
    {
        int idx = oc >> 4, sh = oc & 15;
        for (int p = pair; p < 36; p += 2) {
            int py = p / 6, px = p % 6;
            int w0i = (2 * py) * 12 + 2 * px;
            unsigned v = (unsigned)bs.sgn1[w0i * 8 + idx]        | (unsigned)bs.sgn1[(w0i + 1) * 8 + idx]
                       | (unsigned)bs.sgn1[(w0i + 12) * 8 + idx] | (unsigned)bs.sgn1[(w0i + 13) * 8 + idx];
            unsigned long long m = __ballot(((v >> sh) & 1u) != 0u);
            if (lane == 0) bits2[p * 2 + half] = m;
        }
    }
    __syncthreads();

    // ================= phase 2: binconv2 (6->4) + maxpool(2,s1) (->3) =================
    {
        unsigned long long wr[18];
#pragma unroll
        for (int j = 0; j < 18; j++) wr[j] = wb2[oc * 18 + j];
        const ulonglong2* b2v = (const ulonglong2*)bits2;
        for (int p = pair; p < 9; p += 2) {
            int py = p / 3, px = p % 3;
            int P4[4];
#pragma unroll
            for (int dy = 0; dy < 2; dy++)
#pragma unroll
                for (int dx = 0; dx < 2; dx++) {
                    int P = 0;
#pragma unroll
                    for (int ky = 0; ky < 3; ky++)
#pragma unroll
                        for (int kx = 0; kx < 3; kx++) {
                            ulonglong2 q = b2v[(py + dy + ky) * 6 + (px + dx + kx)];
                            P += __popcll(q.x ^ wr[(ky * 3 + kx) * 2]);
                            P += __popcll(q.y ^ wr[(ky * 3 + kx) * 2 + 1]);
                        }
                    P4[dy * 2 + dx] = P;
                }
            unsigned long long m = __ballot(P4[0] <= 576) | __ballot(P4[1] <= 576) |
                                   __ballot(P4[2] <= 576) | __ballot(P4[3] <= 576);
            if (lane == 0) bits3[p * 2 + half] = m;
        }
    }
    __syncthreads();

    // ================= phase 3: binconv3 + binconv4 + relu + w5 + softmax =================
    if (tid < 128) {
        int P = 0;
#pragma unroll
        for (int k = 0; k < 9; k++) {
            P += __popcll(bits3[k * 2] ^ wb3[tid * 18 + k * 2]);
            P += __popcll(bits3[k * 2 + 1] ^ wb3[tid * 18 + k * 2 + 1]);
        }
        unsigned long long m = __ballot(P <= 576);
        if ((tid & 63) == 0) bits4[tid >> 6] = m;
    }
    __syncthreads();
    if (tid < 128) {
        unsigned long long i0 = bits4[0], i1 = bits4[1];
        int v = 128 - 2 * (int)(__popcll(i0 ^ wb4[tid * 2]) + __popcll(i1 ^ wb4[tid * 2 + 1]));
        r_s[tid] = v > 0 ? (float)v : 0.f;   // relu
    }
    __syncthreads();
    if (tid < NUM_CLS) {
        float l = 0.f;
#pragma unroll 8
        for (int k = 0; k < 128; k++) l = fmaf(w5[tid * 128 + k], r_s[k], l);
        l_s[tid] = l;
    }
    __syncthreads();
    if (tid < NUM_CLS) {
        float mx = -1e30f;
        for (int k = 0; k < NUM_CLS; k++) mx = fmaxf(mx, l_s[k]);
        e_s[tid] = expf(l_s[tid] - mx);
    }
    __syncthreads();
    if (tid < NUM_CLS) {
        float sum = 0.f;
        for (int k = 0; k < NUM_CLS; k++) sum += e_s[k];
        out[(size_t)b * NUM_CLS + tid] = e_s[tid] / sum;
    }
}

extern "C" void kernel_launch(void* const* d_in, const int* in_sizes, int n_in,
                              void* d_out, int out_size, void* d_ws, size_t ws_size,
                              hipStream_t stream) {
    const float* x  = (const float*)d_in[0];
    const float* w0 = (const float*)d_in[1];
    const float* w1 = (const float*)d_in[2];
    const float* w2 = (const float*)d_in[3];
    const float* w3 = (const float*)d_in[4];
    const float* w4 = (const float*)d_in[5];
    const float* w5 = (const float*)d_in[6];
    float* out = (float*)d_out;

    int B = in_sizes[0] / 3072;   // 1024

    size_t off = 0;
    auto carve = [&](size_t bytes) {
        void* p = (char*)d_ws + off;
        off += (bytes + 255) & ~(size_t)255;
        return p;
    };
    unsigned long long* wb2 = (unsigned long long*)carve(1152 * 2 * 8);
    unsigned long long* wb3 = (unsigned long long*)carve(1152 * 2 * 8);
    unsigned long long* wb4 = (unsigned long long*)carve(128 * 2 * 8);
    _Float16* bsig = (_Float16*)carve(8 * 64 * 8 * 2);   // conv0 MFMA B-frags (signed)
    _Float16* babs = (_Float16*)carve(8 * 64 * 8 * 2);   // conv0 MFMA B-frags (abs, unused by fused_net)
    uint4* bw1f = (uint4*)carve(18 * 8 * 64 * 16);       // w1 i8 frags, 147456 B
    (void)ws_size; (void)n_in; (void)out_size;

    prep_all<<<326, 256, 0, stream>>>(w0, w1, w2, w3, w4, wb2, wb3, wb4, bsig, babs, bw1f);
    fused_net<<<B, 256, 0, stream>>>(x, w0, bsig, babs, bw1f, wb2, wb3, wb4, w5, out);
}

// Round 7
// 132.567 us; speedup vs baseline: 2.2336x; 1.0505x over previous
//
#include <hip/hip_runtime.h>
#include <cmath>

#define NUM_CLS 58

typedef _Float16 v8h __attribute__((ext_vector_type(8)));
typedef float v4f __attribute__((ext_vector_type(4)));
typedef int v4i __attribute__((ext_vector_type(4)));
union HU { v8h h; uint4 u; };

// ---------------- prep v5 ----------------
// blocks 0..127   : per-oc binarize of w3 (popcount path, phase 3)
// blocks 128..159 : w4 binarize (1 oc per wave)
// blocks 160..161 : w0 MFMA B-fragments, signed + abs (4 nt per block)
// blocks 162..197 : w1 -> +-1 i8 MFMA B-frags [tk=18][nt=8][lane=64][16B]
// blocks 198..233 : w2 -> same fragment format (binconv2 now MFMA too)
__global__ __launch_bounds__(256) void prep_all(
    const float* __restrict__ w0, const float* __restrict__ w1,
    const float* __restrict__ w2, const float* __restrict__ w3,
    const float* __restrict__ w4,
    unsigned long long* __restrict__ wb3, unsigned long long* __restrict__ wb4,
    _Float16* __restrict__ bsig, _Float16* __restrict__ babs,
    uint4* __restrict__ bw1f, uint4* __restrict__ bw2f) {
    int id = blockIdx.x, tid = threadIdx.x;
    int lane = tid & 63, wv = tid >> 6;
    if (id < 128) {
        int oc = id;
        __shared__ float s[1152];
        const float* base = w3 + (size_t)oc * 1152;
        for (int i = tid; i < 1152; i += 256) s[i] = base[i];   // coalesced
        __syncthreads();
        for (int k = wv; k < 9; k += 4) {    // stride-9 LDS reads: 2-way banks, free
            unsigned long long b0 = __ballot(s[lane * 9 + k] >= 0.f);
            unsigned long long b1 = __ballot(s[(lane + 64) * 9 + k] >= 0.f);
            if (lane == 0) { wb3[(oc * 9 + k) * 2] = b0; wb3[(oc * 9 + k) * 2 + 1] = b1; }
        }
    } else if (id < 160) {
        int oc = (id - 128) * 4 + wv;        // 128 oc over 32 blocks x 4 waves
        unsigned long long b0 = __ballot(w4[oc * 128 + lane] >= 0.f);
        unsigned long long b1 = __ballot(w4[oc * 128 + lane + 64] >= 0.f);
        if (lane == 0) { wb4[oc * 2] = b0; wb4[oc * 2 + 1] = b1; }
    } else if (id < 162) {
        int nt = (id - 160) * 4 + wv;        // 8 nt over 2 blocks x 4 waves
        int n = nt * 16 + (lane & 15);
        int k0 = (lane >> 4) * 8;
#pragma unroll
        for (int j = 0; j < 8; j++) {
            int k = k0 + j;
            float v = (k < 27) ? w0[n * 27 + k] : 0.f;
            bsig[(nt * 64 + lane) * 8 + j] = (_Float16)v;
            babs[(nt * 64 + lane) * 8 + j] = (_Float16)fabsf(v);
        }
    } else {
        // i8 fragments for w1/w2: frag fi=(tk,nt,ln); byte j = sign(w[oc=nt*16+(ln&15)]
        //   [ic=kk*64+(ln>>4)*16+j][tap]) as +1/-1 i8. w idx = oc*1152 + ic*9 + tap.
        bool isw1 = id < 198;
        const float* w = isw1 ? w1 : w2;
        uint4* o = isw1 ? bw1f : bw2f;
        int fi = (isw1 ? id - 162 : id - 198) * 256 + tid;   // 0..9215
        int tk = fi >> 9;                    // 0..17 (tap*2+kk)
        int rem = fi & 511;
        int nt = rem >> 6, ln = rem & 63;
        int oc = nt * 16 + (ln & 15);
        int tap = tk >> 1, kk = tk & 1;
        int icb = kk * 64 + (ln >> 4) * 16;
        const float* wp = w + (size_t)oc * 1152 + tap;
        unsigned int dd[4];
#pragma unroll
        for (int q = 0; q < 4; ++q) {
            unsigned int v = 0;
#pragma unroll
            for (int j = 0; j < 4; ++j)
                v |= (wp[(icb + q * 4 + j) * 9] >= 0.f ? 0x01u : 0xFFu) << (8 * j);
            dd[q] = v;
        }
        uint4 d; d.x = dd[0]; d.y = dd[1]; d.z = dd[2]; d.w = dd[3];
        o[fi] = d;
    }
}

// LDS overlays: one union carries phase-0 staging, the phase-1 i8 expansion,
// and the phase-2 i8 expansion (each dead before the next is written).
union UEXP {
    struct {
        _Float16 xh[3172];                 // image f16; row stride 33, chan stride 1057
        alignas(16) uint4 bfrag[512];      // conv0 B sign-fragments (8 KB)
    } p0;
    unsigned char expb[225 * 128];         // phase1: +-1 i8 [pos][128B], XOR-swizzled chunks
    struct {
        alignas(16) unsigned char expb2[36 * 128];  // phase2: +-1 i8, 6x6 cells, swizzled
        unsigned short sgn2[16 * 8];                // conv2 window signs [win][nt]
    } p2;
};
union BS {
    alignas(16) unsigned long long bits1[450];  // [15*15][2]
    unsigned short sgn1[144 * 8];               // binconv1 window signs [w][nt]
};

// ---- one block per batch element, 4 waves (REGISTER WALL, measured r1/r2) ----
// r4: binconv1 = EXACT i8 MFMA. r5: XOR swizzle, 79us. r6 POST-MORTEM: fusing
// 1b's nt-passes (acc[5]x2 live) tipped the 64-VGPR wall -> scratch spill
// (WRITE_SIZE 0.8->3.2MB), net neutral. 1b reverted to r5's register-feasible
// unfused form; |B|-in-register (r6 item 1, register-neutral) kept.
// r7: binconv2+pool -> i8 MFMA. conv2's 16 windows = ONE 16x16 m-tile; K=1152
// = 18 k-steps. Expansion from sgn1 absorbs phase 1c and bits2. acc = 8 regs
// (safe). Row set {y2*6+x2} covers all 8 swizzle classes 2x -> 2-way = free.
__global__ __launch_bounds__(256, 4) void fused_net(
    const float* __restrict__ x, const float* __restrict__ w0,
    const _Float16* __restrict__ bsigG, const _Float16* __restrict__ babsG,
    const uint4* __restrict__ bw1f, const uint4* __restrict__ bw2f,
    const unsigned long long* __restrict__ wb3, const unsigned long long* __restrict__ wb4,
    const float* __restrict__ w5, float* __restrict__ out) {
    __shared__ UEXP u;
    __shared__ BS bs;
    __shared__ unsigned int lut[16];
    __shared__ unsigned long long bits3[18];
    __shared__ unsigned long long bits4[2];
    __shared__ float r_s[128];
    __shared__ float l_s[NUM_CLS];
    __shared__ float e_s[NUM_CLS];
    __shared__ unsigned int qcnt;
    __shared__ unsigned int queue[256];

    int b = blockIdx.x;
    int tid = threadIdx.x;
    int lane = tid & 63, wave = tid >> 6;
    const float* xb = x + (size_t)b * 3072;
    (void)babsG;   // |B| derived in-register from bsigG fragments

    // nibble -> 4 bytes of +-1 i8 LUT (used by both expansions)
    if (tid < 16) {
        unsigned int v = 0;
#pragma unroll
        for (int j = 0; j < 4; ++j) v |= (((tid >> j) & 1) ? 0x01u : 0xFFu) << (8 * j);
        lut[tid] = v;
    }

    // ================= phase 0: conv0 via f16 MFMA (pool-ordered im2col) =================
    {
        for (int i = tid; i < 3072; i += 256) {
            int c = i >> 10, rem = i & 1023;
            u.p0.xh[c * 1057 + (rem >> 5) * 33 + (rem & 31)] = (_Float16)xb[i];
        }
        const uint4* bs4 = (const uint4*)bsigG;
        for (int i = tid; i < 512; i += 256) u.p0.bfrag[i] = bs4[i];
        if (tid == 0) qcnt = 0;

        int k0 = (lane >> 4) * 8;
        int offj[8];
#pragma unroll
        for (int j = 0; j < 8; j++) {
            int k = k0 + j;
            int c = k / 9, r = (k % 9) / 3, q = k % 3;
            offj[j] = c * 1057 + r * 33 + q;
        }
        unsigned short* b1u16 = (unsigned short*)bs.bits1;
        __syncthreads();

        for (int mt = wave; mt < 57; mt += 4) {   // M = 225*4 = 900 -> 57 tiles
            int mg = mt * 16 + (lane & 15);
            int me = mg < 900 ? mg : 899;
            int p = me >> 2, win = me & 3;
            int py = p / 15, px = p - py * 15;
            int base = (py * 2 + (win >> 1)) * 33 + px * 2 + (win & 1);
            v8h a;
#pragma unroll
            for (int j = 0; j < 8; j++)
                a[j] = (k0 + j < 27) ? u.p0.xh[base + offj[j]] : (_Float16)0.f;
            HU ua; ua.h = a;                      // |A| for the error-bound MFMA
            ua.u.x &= 0x7FFF7FFFu; ua.u.y &= 0x7FFF7FFFu;
            ua.u.z &= 0x7FFF7FFFu; ua.u.w &= 0x7FFF7FFFu;
            int myp = mt * 4 + (lane >> 4);
#pragma unroll
            for (int nt = 0; nt < 8; nt++) {
                HU bsf; bsf.u = u.p0.bfrag[nt * 64 + lane];
                HU baf;                           // |B| in-register: f16 abs = clear sign bits
                baf.u.x = bsf.u.x & 0x7FFF7FFFu; baf.u.y = bsf.u.y & 0x7FFF7FFFu;
                baf.u.z = bsf.u.z & 0x7FFF7FFFu; baf.u.w = bsf.u.w & 0x7FFF7FFFu;
                v4f s  = __builtin_amdgcn_mfma_f32_16x16x32_f16(a,    bsf.h, (v4f){0.f,0.f,0.f,0.f}, 0, 0, 0);
                v4f sa = __builtin_amdgcn_mfma_f32_16x16x32_f16(ua.h, baf.h, (v4f){0.f,0.f,0.f,0.f}, 0, 0, 0);
                // rigorous f16-rounding bounds; sign logic as wave-mask ballots
                float bd0 = fmaf(sa[0], 1.1e-3f, 1e-5f);
                float bd1 = fmaf(sa[1], 1.1e-3f, 1e-5f);
                float bd2 = fmaf(sa[2], 1.1e-3f, 1e-5f);
                float bd3 = fmaf(sa[3], 1.1e-3f, 1e-5f);
                unsigned long long mkpos =
                    __ballot(s[0] >= bd0) | __ballot(s[1] >= bd1) |
                    __ballot(s[2] >= bd2) | __ballot(s[3] >= bd3);
                unsigned long long mkunc =
                    (__ballot(fabsf(s[0]) < bd0) | __ballot(fabsf(s[1]) < bd1) |
                     __ballot(fabsf(s[2]) < bd2) | __ballot(fabsf(s[3]) < bd3)) & ~mkpos;
                if ((lane & 15) == 0 && myp < 225)
                    b1u16[myp * 8 + nt] = (unsigned short)(mkpos >> (lane & 48));
                if (__builtin_expect(mkunc != 0ull, 0)) {
                    if (((mkunc >> lane) & 1ull) && myp < 225) {
                        unsigned int qi = atomicAdd(&qcnt, 1u);
                        if (qi < 256) queue[qi] = (unsigned)myp | ((unsigned)(nt * 16 + (lane & 15)) << 8);
                    }
                }
            }
        }
        __syncthreads();
        // ---- drain queue: exact f64 signs from GLOBAL f32 x (rare; all 4 windows) ----
        unsigned int nq = qcnt < 256u ? qcnt : 256u;
        for (unsigned int i = tid; i < nq; i += 256) {
            unsigned int e = queue[i];
            int p = e & 255; int oc = (e >> 8) & 255;
            int py = p / 15, px = p - py * 15;
            bool pos = false;
#pragma unroll
            for (int win = 0; win < 4; win++) {
                int base = (py * 2 + (win >> 1)) * 32 + px * 2 + (win & 1);
                double sd = 0.0;
#pragma unroll
                for (int k = 0; k < 27; k++) {
                    int c = k / 9, r = (k % 9) / 3, q = k % 3;
                    sd += (double)xb[base + c * 1024 + r * 32 + q] * (double)w0[oc * 27 + k];
                }
                pos |= (sd >= 0.0);
            }
            if (pos) atomicOr(&bs.bits1[p * 2 + (oc >> 6)], 1ull << (oc & 63));
        }
    }
    __syncthreads();

    // ========== phase 1a: expand bits1 -> +-1 i8 [225][128B], XOR-swizzled chunks ==========
    if (tid < 225) {
        ulonglong2 bw = ((const ulonglong2*)bs.bits1)[tid];
        unsigned char* dst = u.expb + tid * 128;
        int sw = (tid & 7) << 4;                   // row-XOR swizzle
#pragma unroll
        for (int c2 = 0; c2 < 2; ++c2) {
            unsigned long long v = c2 ? bw.y : bw.x;
#pragma unroll
            for (int c = 0; c < 4; ++c) {
                uint4 d;
                d.x = lut[(v >> (c * 16 +  0)) & 15];
                d.y = lut[(v >> (c * 16 +  4)) & 15];
                d.z = lut[(v >> (c * 16 +  8)) & 15];
                d.w = lut[(v >> (c * 16 + 12)) & 15];
                *(uint4*)(dst + (((c2 * 4 + c) * 16) ^ sw)) = d;
            }
        }
    }
    __syncthreads();

    // ========== phase 1b: binconv1 via i8 MFMA (r5 unfused form — register-safe) ==========
    {
        int pg_[9];                                // pos*128 + (lane>>4)*16
#pragma unroll
        for (int mt = 0; mt < 9; ++mt) {
            int w = mt * 16 + (lane & 15);         // window row 0..143
            int wy = w / 12, wx = w - wy * 12;
            pg_[mt] = (wy * 15 + wx) * 128 + ((lane >> 4) << 4);
        }

        for (int pass = 0; pass < 2; ++pass) {
            int nt = wave * 2 + pass;
            v4i acc[9];
#pragma unroll
            for (int mt = 0; mt < 9; ++mt) acc[mt] = (v4i){0, 0, 0, 0};
#pragma unroll 2
            for (int tk = 0; tk < 18; ++tk) {      // tap*2+kk
                int tap = tk >> 1, kk = tk & 1;
                int tapoff = tap + (tap / 3) * 12; // ky*15+kx
                int tks = tapoff * 128 + kk * 64;
                uint4 bfr = bw1f[(tk * 8 + nt) * 64 + lane];
                v4i bf; bf.x = (int)bfr.x; bf.y = (int)bfr.y; bf.z = (int)bfr.z; bf.w = (int)bfr.w;
#pragma unroll
                for (int mt = 0; mt < 9; ++mt) {
                    // row = pos+tapoff; chunk<128 never carries into bit7, so
                    // full ^ ((full>>3)&0x70) == row*128 + (chunk16 ^ ((row&7)<<4))
                    int full = pg_[mt] + tks;
                    int addr = full ^ ((full >> 3) & 0x70);
                    v4i af = *(const v4i*)(u.expb + addr);
                    acc[mt] = __builtin_amdgcn_mfma_i32_16x16x64_i8(af, bf, acc[mt], 0, 0, 0);
                }
            }
            // signs -> sgn1[w][nt] as u16 oc-slices (same ballot idiom as phase 0)
#pragma unroll
            for (int mt = 0; mt < 9; ++mt) {
#pragma unroll
                for (int r = 0; r < 4; ++r) {
                    unsigned long long mm = __ballot(acc[mt][r] >= 0);
                    if ((lane & 15) == 0)
                        bs.sgn1[(mt * 16 + (lane >> 4) * 4 + r) * 8 + nt] =
                            (unsigned short)(mm >> lane);
                }
            }
        }
    }
    __syncthreads();

    // ========== phase 2a: pool(sgn1) -> +-1 i8 expb2 [36 cells][128B], swizzled ==========
    // Folds the old phase-1c pooling + bits2 into the expansion: cell value =
    // OR of the 4 conv1 windows under the 2x2 s2 pool.
    if (tid < 144) {
        int cell = tid >> 2, cg = tid & 3;        // cell 0..35, 32-channel group
        int cy = cell / 6, cx = cell - cy * 6;
        int w0i = (2 * cy) * 12 + 2 * cx;
        int g0 = cg * 2, g1 = cg * 2 + 1;
        unsigned v0 = (unsigned)bs.sgn1[w0i * 8 + g0]        | (unsigned)bs.sgn1[(w0i + 1) * 8 + g0]
                    | (unsigned)bs.sgn1[(w0i + 12) * 8 + g0] | (unsigned)bs.sgn1[(w0i + 13) * 8 + g0];
        unsigned v1 = (unsigned)bs.sgn1[w0i * 8 + g1]        | (unsigned)bs.sgn1[(w0i + 1) * 8 + g1]
                    | (unsigned)bs.sgn1[(w0i + 12) * 8 + g1] | (unsigned)bs.sgn1[(w0i + 13) * 8 + g1];
        unsigned vv = v0 | (v1 << 16);
        int sw = (cell & 7) << 4;
        unsigned char* dst = u.p2.expb2 + cell * 128;
        uint4 d0, d1;
        d0.x = lut[vv & 15];         d0.y = lut[(vv >> 4) & 15];
        d0.z = lut[(vv >> 8) & 15];  d0.w = lut[(vv >> 12) & 15];
        d1.x = lut[(vv >> 16) & 15]; d1.y = lut[(vv >> 20) & 15];
        d1.z = lut[(vv >> 24) & 15]; d1.w = lut[(vv >> 28) & 15];
        *(uint4*)(dst + ((cg * 32) ^ sw)) = d0;
        *(uint4*)(dst + ((cg * 32 + 16) ^ sw)) = d1;
    }
    __syncthreads();

    // ========== phase 2b: binconv2 via i8 MFMA — 16 windows = one m-tile ==========
    {
        int m = lane & 15;                         // conv2 window y2*4+x2
        int y2 = m >> 2, x2 = m & 3;
        int pg2 = (y2 * 6 + x2) * 128 + ((lane >> 4) << 4);
        int ntA = wave * 2, ntB = wave * 2 + 1;
        v4i acc0 = (v4i){0, 0, 0, 0}, acc1 = (v4i){0, 0, 0, 0};
#pragma unroll 2
        for (int tk = 0; tk < 18; ++tk) {
            int tap = tk >> 1, kk = tk & 1;
            int tapoff2 = (tap / 3) * 6 + (tap % 3);   // ky*6+kx
            int tks = tapoff2 * 128 + kk * 64;
            uint4 br0 = bw2f[(tk * 8 + ntA) * 64 + lane];
            uint4 br1 = bw2f[(tk * 8 + ntB) * 64 + lane];
            v4i b0; b0.x = (int)br0.x; b0.y = (int)br0.y; b0.z = (int)br0.z; b0.w = (int)br0.w;
            v4i b1; b1.x = (int)br1.x; b1.y = (int)br1.y; b1.z = (int)br1.z; b1.w = (int)br1.w;
            int full = pg2 + tks;
            int addr = full ^ ((full >> 3) & 0x70);
            v4i af = *(const v4i*)(u.p2.expb2 + addr);
            acc0 = __builtin_amdgcn_mfma_i32_16x16x64_i8(af, b0, acc0, 0, 0, 0);
            acc1 = __builtin_amdgcn_mfma_i32_16x16x64_i8(af, b1, acc1, 0, 0, 0);
        }
#pragma unroll
        for (int r = 0; r < 4; ++r) {
            unsigned long long m0 = __ballot(acc0[r] >= 0);
            unsigned long long m1 = __ballot(acc1[r] >= 0);
            if ((lane & 15) == 0) {
                u.p2.sgn2[(((lane >> 4) * 4 + r)) * 8 + ntA] = (unsigned short)(m0 >> lane);
                u.p2.sgn2[(((lane >> 4) * 4 + r)) * 8 + ntB] = (unsigned short)(m1 >> lane);
            }
        }
    }
    __syncthreads();

    // ========== phase 2c: maxpool(2,s1) over conv2 window signs -> bits3 ==========
    if (tid < 128) {
        int idx = tid >> 4, sh = tid & 15;         // oc = tid
        int half = tid >> 6;
        for (int p = 0; p < 9; ++p) {
            int py = p / 3, px = p - py * 3;
            int m00 = py * 4 + px;
            unsigned v = (unsigned)u.p2.sgn2[m00 * 8 + idx]       | (unsigned)u.p2.sgn2[(m00 + 1) * 8 + idx]
                       | (unsigned)u.p2.sgn2[(m00 + 4) * 8 + idx] | (unsigned)u.p2.sgn2[(m00 + 5) * 8 + idx];
            unsigned long long mm = __ballot(((v >> sh) & 1u) != 0u);
            if ((tid & 63) == 0) bits3[p * 2 + half] = mm;
        }
    }
    __syncthreads();

    // ================= phase 3: binconv3 + binconv4 + relu + w5 + softmax =================
    if (tid < 128) {
        int P = 0;
#pragma unroll
        for (int k = 0; k < 9; k++) {
            P += __popcll(bits3[k * 2] ^ wb3[tid * 18 + k * 2]);
            P += __popcll(bits3[k * 2 + 1] ^ wb3[tid * 18 + k * 2 + 1]);
        }
        unsigned long long m = __ballot(P <= 576);
        if ((tid & 63) == 0) bits4[tid >> 6] = m;
    }
    __syncthreads();
    if (tid < 128) {
        unsigned long long i0 = bits4[0], i1 = bits4[1];
        int v = 128 - 2 * (int)(__popcll(i0 ^ wb4[tid * 2]) + __popcll(i1 ^ wb4[tid * 2 + 1]));
        r_s[tid] = v > 0 ? (float)v : 0.f;   // relu
    }
    __syncthreads();
    if (tid < NUM_CLS) {
        float l = 0.f;
#pragma unroll 8
        for (int k = 0; k < 128; k++) l = fmaf(w5[tid * 128 + k], r_s[k], l);
        l_s[tid] = l;
    }
    __syncthreads();
    if (tid < NUM_CLS) {
        float mx = -1e30f;
        for (int k = 0; k < NUM_CLS; k++) mx = fmaxf(mx, l_s[k]);
        e_s[tid] = expf(l_s[tid] - mx);
    }
    __syncthreads();
    if (tid < NUM_CLS) {
        float sum = 0.f;
        for (int k = 0; k < NUM_CLS; k++) sum += e_s[k];
        out[(size_t)b * NUM_CLS + tid] = e_s[tid] / sum;
    }
}

extern "C" void kernel_launch(void* const* d_in, const int* in_sizes, int n_in,
                              void* d_out, int out_size, void* d_ws, size_t ws_size,
                              hipStream_t stream) {
    const float* x  = (const float*)d_in[0];
    const float* w0 = (const float*)d_in[1];
    const float* w1 = (const float*)d_in[2];
    const float* w2 = (const float*)d_in[3];
    const float* w3 = (const float*)d_in[4];
    const float* w4 = (const float*)d_in[5];
    const float* w5 = (const float*)d_in[6];
    float* out = (float*)d_out;

    int B = in_sizes[0] / 3072;   // 1024

    size_t off = 0;
    auto carve = [&](size_t bytes) {
        void* p = (char*)d_ws + off;
        off += (bytes + 255) & ~(size_t)255;
        return p;
    };
    unsigned long long* wb3 = (unsigned long long*)carve(1152 * 2 * 8);
    unsigned long long* wb4 = (unsigned long long*)carve(128 * 2 * 8);
    _Float16* bsig = (_Float16*)carve(8 * 64 * 8 * 2);   // conv0 MFMA B-frags (signed)
    _Float16* babs = (_Float16*)carve(8 * 64 * 8 * 2);   // conv0 MFMA B-frags (abs, unused by fused_net)
    uint4* bw1f = (uint4*)carve(18 * 8 * 64 * 16);       // w1 i8 frags, 147456 B
    uint4* bw2f = (uint4*)carve(18 * 8 * 64 * 16);       // w2 i8 frags, 147456 B
    (void)ws_size; (void)n_in; (void)out_size;

    prep_all<<<234, 256, 0, stream>>>(w0, w1, w2, w3, w4, wb3, wb4, bsig, babs, bw1f, bw2f);
    fused_net<<<B, 256, 0, stream>>>(x, w0, bsig, babs, bw1f, bw2f, wb3, wb4, w5, out);
}